// Round 2
// baseline (1070.272 us; speedup 1.0000x reference)
//
#include <hip/hip_runtime.h>

#define D 64
#define H 64
#define EFD 16
#define MS 68    // LDS tile row stride (floats), 16B-aligned
#define TE 128   // edges per block
#define TN 128   // nodes per block

__device__ __forceinline__ float silu(float x) {
    return x / (1.0f + __expf(-x));
}

// acc[j] += sum_kk a[kk] * b[kk][j], b stored as float4 bf[4] (bp[kk*4+j])
#define GEMM_STEP(acc_, a_, bf_) do { \
    const float* bp_ = (const float*)(bf_); \
    acc_[0] += (a_).x*bp_[0] + (a_).y*bp_[4] + (a_).z*bp_[8]  + (a_).w*bp_[12]; \
    acc_[1] += (a_).x*bp_[1] + (a_).y*bp_[5] + (a_).z*bp_[9]  + (a_).w*bp_[13]; \
    acc_[2] += (a_).x*bp_[2] + (a_).y*bp_[6] + (a_).z*bp_[10] + (a_).w*bp_[14]; \
    acc_[3] += (a_).x*bp_[3] + (a_).y*bp_[7] + (a_).z*bp_[11] + (a_).w*bp_[15]; \
} while (0)

// one 16-k4-step partial GEMM over smem rows [8eg..], W rows [wrow0..wrow0+63]
#define PGEMM64(acc_, Wp_, wrow0_, eg_, hg_, smem_) do { \
    for (int k4 = 0; k4 < 16; k4++) { \
        float4 bf_[4]; \
        _Pragma("unroll") \
        for (int kk = 0; kk < 4; kk++) \
            bf_[kk] = *(const float4*)&(Wp_)[(size_t)((wrow0_) + 4*k4 + kk) * H + 4*(hg_)]; \
        _Pragma("unroll") \
        for (int i = 0; i < 8; i++) { \
            float4 a_ = *(const float4*)&(smem_)[(8*(eg_) + i) * MS + 4*k4]; \
            GEMM_STEP(acc_[i], a_, bf_); \
        } \
    } \
} while (0)

__global__ __launch_bounds__(256, 4) void edge_kernel(
    const float* __restrict__ node_feat,
    const float* __restrict__ coord,
    const float* __restrict__ edge_feat,
    const int* __restrict__ src,
    const int* __restrict__ dst,
    const float* __restrict__ W_e1, const float* __restrict__ b_e1,
    const float* __restrict__ W_e2, const float* __restrict__ b_e2,
    float* __restrict__ h_neigh,
    int E)
{
    __shared__ float smem[TE * MS];   // one 34.8 KB tile, reused across phases
    __shared__ int sidx[2 * TE];      // src | dst

    const int tid = threadIdx.x;
    const int ebase = blockIdx.x * TE;

    if (tid < TE) {
        int e = ebase + tid;
        int s = 0, d2 = 0;
        if (e < E) { s = src[e]; d2 = dst[e]; }
        sidx[tid] = s;
        sidx[TE + tid] = d2;
    }
    __syncthreads();

    const int eg = tid >> 4;   // 0..15 -> 8 edges each
    const int hg = tid & 15;   // 0..15 -> 4 outs each

    float acc[8][4];
    {
        float4 b0 = *(const float4*)&b_e1[4*hg];
        #pragma unroll
        for (int i = 0; i < 8; i++) {
            acc[i][0]=b0.x; acc[i][1]=b0.y; acc[i][2]=b0.z; acc[i][3]=b0.w;
        }
    }

    // ---- phase A: h_src tile, W_e1 rows 0..63 ----
    {
        const int k = tid & 63, eo = tid >> 6;
        for (int e = eo; e < TE; e += 4)
            smem[e * MS + k] = node_feat[(size_t)sidx[e] * D + k];
    }
    __syncthreads();
    PGEMM64(acc, W_e1, 0, eg, hg, smem);
    __syncthreads();

    // ---- phase B: h_dst tile, W_e1 rows 64..127 ----
    {
        const int k = tid & 63, eo = tid >> 6;
        for (int e = eo; e < TE; e += 4)
            smem[e * MS + k] = node_feat[(size_t)sidx[TE + e] * D + k];
    }
    __syncthreads();
    PGEMM64(acc, W_e1, 64, eg, hg, smem);
    __syncthreads();

    // ---- phase C: [radial | edge_feat] (17 cols), W_e1 rows 128..144 ----
    {
        const int k2 = tid & 15, e2 = tid >> 4;
        for (int e = e2; e < TE; e += 16) {
            int ge = ebase + e;
            smem[e * MS + 1 + k2] = (ge < E) ? edge_feat[(size_t)ge * EFD + k2] : 0.f;
        }
        if (tid < TE) {
            int s = sidx[tid], d2 = sidx[TE + tid];
            float dx = coord[s*3+0] - coord[d2*3+0];
            float dy = coord[s*3+1] - coord[d2*3+1];
            float dz = coord[s*3+2] - coord[d2*3+2];
            smem[tid * MS + 0] = dx*dx + dy*dy + dz*dz;
        }
    }
    __syncthreads();
    for (int k4 = 0; k4 < 4; k4++) {
        float4 bf[4];
        #pragma unroll
        for (int kk = 0; kk < 4; kk++)
            bf[kk] = *(const float4*)&W_e1[(size_t)(128 + 4*k4 + kk) * H + 4*hg];
        #pragma unroll
        for (int i = 0; i < 8; i++) {
            float4 a = *(const float4*)&smem[(8*eg + i) * MS + 4*k4];
            GEMM_STEP(acc[i], a, bf);
        }
    }
    {   // tail k = 16 -> W_e1 row 144
        float4 b = *(const float4*)&W_e1[(size_t)144 * H + 4*hg];
        #pragma unroll
        for (int i = 0; i < 8; i++) {
            float a = smem[(8*eg+i)*MS + 16];
            acc[i][0] += a*b.x; acc[i][1] += a*b.y; acc[i][2] += a*b.z; acc[i][3] += a*b.w;
        }
    }
    __syncthreads();

    // ---- m = silu(acc) into smem [TE][MS] cols 0..63 ----
    #pragma unroll
    for (int i = 0; i < 8; i++) {
        float4 mv;
        mv.x = silu(acc[i][0]); mv.y = silu(acc[i][1]);
        mv.z = silu(acc[i][2]); mv.w = silu(acc[i][3]);
        *(float4*)&smem[(8*eg+i)*MS + 4*hg] = mv;
    }
    __syncthreads();

    // ---- MLP2: [TE,64] @ W_e2[64,64] + b, silu, scatter ----
    float acc2[8][4];
    {
        float4 b0 = *(const float4*)&b_e2[4*hg];
        #pragma unroll
        for (int i = 0; i < 8; i++) {
            acc2[i][0]=b0.x; acc2[i][1]=b0.y; acc2[i][2]=b0.z; acc2[i][3]=b0.w;
        }
    }
    PGEMM64(acc2, W_e2, 0, eg, hg, smem);

    const int emax = E - ebase;
    #pragma unroll
    for (int i = 0; i < 8; i++) {
        int e = 8*eg + i;
        if (e < emax) {
            float* hp = &h_neigh[(size_t)sidx[TE + e] * H + 4*hg];
            atomicAdd(&hp[0], silu(acc2[i][0]));
            atomicAdd(&hp[1], silu(acc2[i][1]));
            atomicAdd(&hp[2], silu(acc2[i][2]));
            atomicAdd(&hp[3], silu(acc2[i][3]));
        }
    }
}

__global__ __launch_bounds__(256, 4) void node_kernel(
    const float* __restrict__ node_feat,
    const float* __restrict__ h_neigh,
    const float* __restrict__ W_n1, const float* __restrict__ b_n1,
    const float* __restrict__ W_n2, const float* __restrict__ b_n2,
    float* __restrict__ out, int N)
{
    __shared__ float smem[TN * MS];  // one 34.8 KB tile, reused across phases

    const int tid = threadIdx.x;
    const int nbase = blockIdx.x * TN;

    const int ng = tid >> 4;
    const int hg = tid & 15;

    float acc[8][4];
    {
        float4 b0 = *(const float4*)&b_n1[4*hg];
        #pragma unroll
        for (int i = 0; i < 8; i++) {
            acc[i][0]=b0.x; acc[i][1]=b0.y; acc[i][2]=b0.z; acc[i][3]=b0.w;
        }
    }

    // ---- phase A: node_feat tile, W_n1 rows 0..63 ----
    {
        const int k = tid & 63, no = tid >> 6;
        for (int n = no; n < TN; n += 4) {
            int gn = nbase + n;
            int cg = (gn < N) ? gn : (N - 1);
            smem[n*MS + k] = node_feat[(size_t)cg * D + k];
        }
    }
    __syncthreads();
    PGEMM64(acc, W_n1, 0, ng, hg, smem);
    __syncthreads();

    // ---- phase B: h_neigh tile, W_n1 rows 64..127 ----
    {
        const int k = tid & 63, no = tid >> 6;
        for (int n = no; n < TN; n += 4) {
            int gn = nbase + n;
            int cg = (gn < N) ? gn : (N - 1);
            smem[n*MS + k] = h_neigh[(size_t)cg * H + k];
        }
    }
    __syncthreads();
    PGEMM64(acc, W_n1, 64, ng, hg, smem);
    __syncthreads();

    // ---- y1 = silu(acc) into smem cols 0..63 ----
    #pragma unroll
    for (int i = 0; i < 8; i++) {
        float4 mv;
        mv.x = silu(acc[i][0]); mv.y = silu(acc[i][1]);
        mv.z = silu(acc[i][2]); mv.w = silu(acc[i][3]);
        *(float4*)&smem[(8*ng+i)*MS + 4*hg] = mv;
    }
    __syncthreads();

    // ---- MLP2: [TN,64] @ W_n2[64,64] + b, store ----
    float acc2[8][4];
    {
        float4 b0 = *(const float4*)&b_n2[4*hg];
        #pragma unroll
        for (int i = 0; i < 8; i++) {
            acc2[i][0]=b0.x; acc2[i][1]=b0.y; acc2[i][2]=b0.z; acc2[i][3]=b0.w;
        }
    }
    PGEMM64(acc2, W_n2, 0, ng, hg, smem);

    #pragma unroll
    for (int i = 0; i < 8; i++) {
        int gn = nbase + 8*ng + i;
        if (gn < N) {
            float4 ov;
            ov.x = acc2[i][0]; ov.y = acc2[i][1]; ov.z = acc2[i][2]; ov.w = acc2[i][3];
            *(float4*)&out[(size_t)gn * D + 4*hg] = ov;
        }
    }
}

extern "C" void kernel_launch(void* const* d_in, const int* in_sizes, int n_in,
                              void* d_out, int out_size, void* d_ws, size_t ws_size,
                              hipStream_t stream)
{
    const float* node_feat = (const float*)d_in[0];
    const float* coord     = (const float*)d_in[1];
    const float* edge_feat = (const float*)d_in[2];
    const int*   src       = (const int*)d_in[3];
    const int*   dst       = (const int*)d_in[4];
    const float* W_e1 = (const float*)d_in[5];
    const float* b_e1 = (const float*)d_in[6];
    const float* W_e2 = (const float*)d_in[7];
    const float* b_e2 = (const float*)d_in[8];
    const float* W_n1 = (const float*)d_in[9];
    const float* b_n1 = (const float*)d_in[10];
    const float* W_n2 = (const float*)d_in[11];
    const float* b_n2 = (const float*)d_in[12];

    const int N = in_sizes[0] / D;
    const int E = in_sizes[3];

    float* h_neigh = (float*)d_ws;
    hipMemsetAsync(h_neigh, 0, (size_t)N * H * sizeof(float), stream);

    const int eblocks = (E + TE - 1) / TE;
    edge_kernel<<<eblocks, 256, 0, stream>>>(node_feat, coord, edge_feat, src, dst,
                                             W_e1, b_e1, W_e2, b_e2, h_neigh, E);

    const int nblocks = (N + TN - 1) / TN;
    node_kernel<<<nblocks, 256, 0, stream>>>(node_feat, h_neigh,
                                             W_n1, b_n1, W_n2, b_n2,
                                             (float*)d_out, N);
}

// Round 4
// 760.491 us; speedup vs baseline: 1.4073x; 1.4073x over previous
//
#include <hip/hip_runtime.h>

#define D 64
#define H 64
#define EFD 16
#define MS 68    // LDS tile row stride (floats), 16B-aligned
#define TE 128   // edges per block
#define TN 128   // nodes per block

__device__ __forceinline__ float silu(float x) {
    return x / (1.0f + __expf(-x));
}

// acc[j] += sum_kk a[kk] * b[kk][j], b stored as float4 bf[4] (bp[kk*4+j])
#define GEMM_STEP(acc_, a_, bf_) do { \
    const float* bp_ = (const float*)(bf_); \
    acc_[0] += (a_).x*bp_[0] + (a_).y*bp_[4] + (a_).z*bp_[8]  + (a_).w*bp_[12]; \
    acc_[1] += (a_).x*bp_[1] + (a_).y*bp_[5] + (a_).z*bp_[9]  + (a_).w*bp_[13]; \
    acc_[2] += (a_).x*bp_[2] + (a_).y*bp_[6] + (a_).z*bp_[10] + (a_).w*bp_[14]; \
    acc_[3] += (a_).x*bp_[3] + (a_).y*bp_[7] + (a_).z*bp_[11] + (a_).w*bp_[15]; \
} while (0)

// one 16-k4-step partial GEMM over smem rows [8eg..], W rows [wrow0..wrow0+63]
#define PGEMM64(acc_, Wp_, wrow0_, eg_, hg_, smem_) do { \
    for (int k4 = 0; k4 < 16; k4++) { \
        float4 bf_[4]; \
        _Pragma("unroll") \
        for (int kk = 0; kk < 4; kk++) \
            bf_[kk] = *(const float4*)&(Wp_)[(size_t)((wrow0_) + 4*k4 + kk) * H + 4*(hg_)]; \
        _Pragma("unroll") \
        for (int i = 0; i < 8; i++) { \
            float4 a_ = *(const float4*)&(smem_)[(8*(eg_) + i) * MS + 4*k4]; \
            GEMM_STEP(acc_[i], a_, bf_); \
        } \
    } \
} while (0)

// ---------------- sort-by-dst construction ----------------

__global__ __launch_bounds__(256) void hist_kernel(
    const int* __restrict__ dst, int* __restrict__ deg, int E)
{
    int e = blockIdx.x * 256 + threadIdx.x;
    if (e < E) atomicAdd(&deg[dst[e]], 1);
}

__global__ __launch_bounds__(1024, 1) void scan_kernel(
    const int* __restrict__ deg, int* __restrict__ cursor, int N)
{
    __shared__ int wsums[16];
    __shared__ int carry_s;
    const int tid = threadIdx.x;
    const int lane = tid & 63, wid = tid >> 6;
    if (tid == 0) carry_s = 0;
    __syncthreads();
    for (int base = 0; base < N; base += 1024) {
        int idx = base + tid;
        int v = (idx < N) ? deg[idx] : 0;
        int x = v;
        #pragma unroll
        for (int off = 1; off < 64; off <<= 1) {
            int y = __shfl_up(x, off, 64);
            if (lane >= off) x += y;
        }
        if (lane == 63) wsums[wid] = x;
        __syncthreads();
        if (wid == 0) {
            int ws = (lane < 16) ? wsums[lane] : 0;
            #pragma unroll
            for (int off = 1; off < 16; off <<= 1) {
                int y = __shfl_up(ws, off, 64);
                if (lane >= off) ws += y;
            }
            if (lane < 16) wsums[lane] = ws;   // inclusive scan of wave sums
        }
        __syncthreads();
        int wprefix = (wid > 0) ? wsums[wid - 1] : 0;
        int excl = carry_s + wprefix + x - v;
        if (idx < N) cursor[idx] = excl;
        __syncthreads();
        if (tid == 0) carry_s += wsums[15];
        __syncthreads();
    }
}

__global__ __launch_bounds__(256) void build_kernel(
    const int* __restrict__ dst, int* __restrict__ cursor,
    int* __restrict__ eidx, int E)
{
    int e = blockIdx.x * 256 + threadIdx.x;
    if (e < E) {
        int pos = atomicAdd(&cursor[dst[e]], 1);
        eidx[pos] = e;
    }
}

// ---------------- edge kernel ----------------
// MODE 0: process edges in natural order, per-edge atomics (fallback).
// MODE 1: process edges in dst-sorted order via eidx, segment-reduce in LDS,
//         one atomic per (segment, channel-group).

template <int MODE>
__global__ __launch_bounds__(256, 4) void edge_kernel(
    const float* __restrict__ node_feat,
    const float* __restrict__ coord,
    const float* __restrict__ edge_feat,
    const int* __restrict__ src,
    const int* __restrict__ dst,
    const int* __restrict__ eidx_g,
    const float* __restrict__ W_e1, const float* __restrict__ b_e1,
    const float* __restrict__ W_e2, const float* __restrict__ b_e2,
    float* __restrict__ h_neigh,
    int E)
{
    __shared__ float smem[TE * MS];
    __shared__ int ssrc[TE];
    __shared__ int sdst[TE];   // -1 for invalid rows
    __shared__ int seid[TE];

    const int tid = threadIdx.x;
    const int ebase = blockIdx.x * TE;

    float radial = 0.f;
    if (tid < TE) {
        int p = ebase + tid;
        int e = p, s = 0, d2 = -1;
        if (p < E) {
            if (MODE == 1) e = eidx_g[p];
            s = src[e];
            d2 = dst[e];
        }
        ssrc[tid] = s;
        sdst[tid] = d2;
        seid[tid] = e;
        if (d2 >= 0) {
            float dx = coord[s*3+0] - coord[d2*3+0];
            float dy = coord[s*3+1] - coord[d2*3+1];
            float dz = coord[s*3+2] - coord[d2*3+2];
            radial = dx*dx + dy*dy + dz*dz;
        }
    }
    __syncthreads();

    const int eg = tid >> 4;   // 0..15 -> 8 edge rows each
    const int hg = tid & 15;   // 0..15 -> 4 out channels each
    const int k  = tid & 63;   // staging column
    const int eo = tid >> 6;   // staging row offset

    float acc[8][4];
    {
        float4 b0 = *(const float4*)&b_e1[4*hg];
        #pragma unroll
        for (int i = 0; i < 8; i++) {
            acc[i][0]=b0.x; acc[i][1]=b0.y; acc[i][2]=b0.z; acc[i][3]=b0.w;
        }
    }

    // ---- issue phase-A gathers (h_src), write to LDS ----
    float rA[32];
    #pragma unroll
    for (int t = 0; t < 32; t++)
        rA[t] = node_feat[(size_t)ssrc[eo + 4*t] * D + k];
    #pragma unroll
    for (int t = 0; t < 32; t++)
        smem[(eo + 4*t) * MS + k] = rA[t];
    __syncthreads();

    // ---- issue phase-B gathers (h_dst) into regs, then compute phase A ----
    float rB[32];
    #pragma unroll
    for (int t = 0; t < 32; t++) {
        int row = sdst[eo + 4*t];
        row = row < 0 ? 0 : row;
        rB[t] = node_feat[(size_t)row * D + k];
    }
    PGEMM64(acc, W_e1, 0, eg, hg, smem);
    __syncthreads();

    #pragma unroll
    for (int t = 0; t < 32; t++)
        smem[(eo + 4*t) * MS + k] = rB[t];
    __syncthreads();

    // ---- issue phase-C loads (edge_feat) into regs, compute phase B ----
    float rC[8];
    {
        const int k2 = tid & 15, e2 = tid >> 4;
        #pragma unroll
        for (int t = 0; t < 8; t++) {
            int r = e2 + 16*t;
            rC[t] = (ebase + r < E) ? edge_feat[(size_t)seid[r] * EFD + k2] : 0.f;
        }
    }
    PGEMM64(acc, W_e1, 64, eg, hg, smem);
    __syncthreads();

    {
        const int k2 = tid & 15, e2 = tid >> 4;
        #pragma unroll
        for (int t = 0; t < 8; t++)
            smem[(e2 + 16*t) * MS + 1 + k2] = rC[t];
        if (tid < TE) smem[tid * MS + 0] = radial;
    }
    __syncthreads();

    // ---- phase C: cols 0..15 <-> W rows 128..143, tail col 16 <-> row 144 ----
    for (int k4 = 0; k4 < 4; k4++) {
        float4 bf[4];
        #pragma unroll
        for (int kk = 0; kk < 4; kk++)
            bf[kk] = *(const float4*)&W_e1[(size_t)(128 + 4*k4 + kk) * H + 4*hg];
        #pragma unroll
        for (int i = 0; i < 8; i++) {
            float4 a = *(const float4*)&smem[(8*eg + i) * MS + 4*k4];
            GEMM_STEP(acc[i], a, bf);
        }
    }
    {
        float4 b = *(const float4*)&W_e1[(size_t)144 * H + 4*hg];
        #pragma unroll
        for (int i = 0; i < 8; i++) {
            float a = smem[(8*eg+i)*MS + 16];
            acc[i][0] += a*b.x; acc[i][1] += a*b.y; acc[i][2] += a*b.z; acc[i][3] += a*b.w;
        }
    }
    __syncthreads();

    // ---- m = silu(acc) into smem cols 0..63 ----
    #pragma unroll
    for (int i = 0; i < 8; i++) {
        float4 mv;
        mv.x = silu(acc[i][0]); mv.y = silu(acc[i][1]);
        mv.z = silu(acc[i][2]); mv.w = silu(acc[i][3]);
        *(float4*)&smem[(8*eg+i)*MS + 4*hg] = mv;
    }
    __syncthreads();

    // ---- MLP2 ----
    float acc2[8][4];
    {
        float4 b0 = *(const float4*)&b_e2[4*hg];
        #pragma unroll
        for (int i = 0; i < 8; i++) {
            acc2[i][0]=b0.x; acc2[i][1]=b0.y; acc2[i][2]=b0.z; acc2[i][3]=b0.w;
        }
    }
    PGEMM64(acc2, W_e2, 0, eg, hg, smem);

    if (MODE == 0) {
        #pragma unroll
        for (int i = 0; i < 8; i++) {
            int r = 8*eg + i;
            int dr = sdst[r];
            if (dr >= 0) {
                float* hp = &h_neigh[(size_t)dr * H + 4*hg];
                atomicAdd(&hp[0], silu(acc2[i][0]));
                atomicAdd(&hp[1], silu(acc2[i][1]));
                atomicAdd(&hp[2], silu(acc2[i][2]));
                atomicAdd(&hp[3], silu(acc2[i][3]));
            }
        }
    } else {
        // write msg = silu(acc2) back to smem, then segment-reduce by dst
        __syncthreads();   // all m reads done
        #pragma unroll
        for (int i = 0; i < 8; i++) {
            float4 mv;
            mv.x = silu(acc2[i][0]); mv.y = silu(acc2[i][1]);
            mv.z = silu(acc2[i][2]); mv.w = silu(acc2[i][3]);
            *(float4*)&smem[(8*eg+i)*MS + 4*hg] = mv;
        }
        __syncthreads();

        int emaxt = E - ebase; if (emaxt > TE) emaxt = TE;
        #pragma unroll 1
        for (int i = 0; i < 8; i++) {
            int r = 8*eg + i;
            if (r >= emaxt) break;
            int dr = sdst[r];
            if (dr < 0) continue;
            if (r > 0 && sdst[r-1] == dr) continue;   // not a segment head
            float4 s = *(const float4*)&smem[r*MS + 4*hg];
            int rr = r + 1;
            while (rr < emaxt && sdst[rr] == dr) {
                const float* mp = &smem[rr*MS + 4*hg];
                s.x += mp[0]; s.y += mp[1]; s.z += mp[2]; s.w += mp[3];
                rr++;
            }
            float* hp = &h_neigh[(size_t)dr * H + 4*hg];
            atomicAdd(&hp[0], s.x); atomicAdd(&hp[1], s.y);
            atomicAdd(&hp[2], s.z); atomicAdd(&hp[3], s.w);
        }
    }
}

// ---------------- node kernel ----------------

__global__ __launch_bounds__(256, 4) void node_kernel(
    const float* __restrict__ node_feat,
    const float* __restrict__ h_neigh,
    const float* __restrict__ W_n1, const float* __restrict__ b_n1,
    const float* __restrict__ W_n2, const float* __restrict__ b_n2,
    float* __restrict__ out, int N)
{
    __shared__ float smem[TN * MS];

    const int tid = threadIdx.x;
    const int nbase = blockIdx.x * TN;

    const int ng = tid >> 4;
    const int hg = tid & 15;
    const int k  = tid & 63;
    const int no = tid >> 6;

    float acc[8][4];
    {
        float4 b0 = *(const float4*)&b_n1[4*hg];
        #pragma unroll
        for (int i = 0; i < 8; i++) {
            acc[i][0]=b0.x; acc[i][1]=b0.y; acc[i][2]=b0.z; acc[i][3]=b0.w;
        }
    }

    // phase A: node_feat rows
    float rA[32];
    #pragma unroll
    for (int t = 0; t < 32; t++) {
        int gn = nbase + no + 4*t;
        int cg = (gn < N) ? gn : (N - 1);
        rA[t] = node_feat[(size_t)cg * D + k];
    }
    #pragma unroll
    for (int t = 0; t < 32; t++)
        smem[(no + 4*t) * MS + k] = rA[t];
    __syncthreads();

    // issue phase B (h_neigh) while computing phase A
    float rB[32];
    #pragma unroll
    for (int t = 0; t < 32; t++) {
        int gn = nbase + no + 4*t;
        int cg = (gn < N) ? gn : (N - 1);
        rB[t] = h_neigh[(size_t)cg * H + k];
    }
    PGEMM64(acc, W_n1, 0, ng, hg, smem);
    __syncthreads();

    #pragma unroll
    for (int t = 0; t < 32; t++)
        smem[(no + 4*t) * MS + k] = rB[t];
    __syncthreads();

    PGEMM64(acc, W_n1, 64, ng, hg, smem);
    __syncthreads();

    #pragma unroll
    for (int i = 0; i < 8; i++) {
        float4 mv;
        mv.x = silu(acc[i][0]); mv.y = silu(acc[i][1]);
        mv.z = silu(acc[i][2]); mv.w = silu(acc[i][3]);
        *(float4*)&smem[(8*ng+i)*MS + 4*hg] = mv;
    }
    __syncthreads();

    float acc2[8][4];
    {
        float4 b0 = *(const float4*)&b_n2[4*hg];
        #pragma unroll
        for (int i = 0; i < 8; i++) {
            acc2[i][0]=b0.x; acc2[i][1]=b0.y; acc2[i][2]=b0.z; acc2[i][3]=b0.w;
        }
    }
    PGEMM64(acc2, W_n2, 0, ng, hg, smem);

    #pragma unroll
    for (int i = 0; i < 8; i++) {
        int gn = nbase + 8*ng + i;
        if (gn < N) {
            float4 ov;
            ov.x = acc2[i][0]; ov.y = acc2[i][1]; ov.z = acc2[i][2]; ov.w = acc2[i][3];
            *(float4*)&out[(size_t)gn * D + 4*hg] = ov;
        }
    }
}

extern "C" void kernel_launch(void* const* d_in, const int* in_sizes, int n_in,
                              void* d_out, int out_size, void* d_ws, size_t ws_size,
                              hipStream_t stream)
{
    const float* node_feat = (const float*)d_in[0];
    const float* coord     = (const float*)d_in[1];
    const float* edge_feat = (const float*)d_in[2];
    const int*   src       = (const int*)d_in[3];
    const int*   dst       = (const int*)d_in[4];
    const float* W_e1 = (const float*)d_in[5];
    const float* b_e1 = (const float*)d_in[6];
    const float* W_e2 = (const float*)d_in[7];
    const float* b_e2 = (const float*)d_in[8];
    const float* W_n1 = (const float*)d_in[9];
    const float* b_n1 = (const float*)d_in[10];
    const float* W_n2 = (const float*)d_in[11];
    const float* b_n2 = (const float*)d_in[12];

    const int N = in_sizes[0] / D;
    const int E = in_sizes[3];

    const size_t hn_b   = (size_t)N * H * sizeof(float);
    const size_t deg_b  = (size_t)N * sizeof(int);
    const size_t cur_b  = (size_t)N * sizeof(int);
    const size_t eidx_b = (size_t)E * sizeof(int);
    const bool sorted = ws_size >= hn_b + deg_b + cur_b + eidx_b;

    float* h_neigh = (float*)d_ws;
    const int eblocks = (E + TE - 1) / TE;

    if (sorted) {
        int* deg    = (int*)((char*)d_ws + hn_b);
        int* cursor = (int*)((char*)deg + deg_b);
        int* eidx   = (int*)((char*)cursor + cur_b);
        hipMemsetAsync(d_ws, 0, hn_b + deg_b, stream);
        hist_kernel<<<(E + 255) / 256, 256, 0, stream>>>(dst, deg, E);
        scan_kernel<<<1, 1024, 0, stream>>>(deg, cursor, N);
        build_kernel<<<(E + 255) / 256, 256, 0, stream>>>(dst, cursor, eidx, E);
        edge_kernel<1><<<eblocks, 256, 0, stream>>>(node_feat, coord, edge_feat,
                                                    src, dst, eidx,
                                                    W_e1, b_e1, W_e2, b_e2,
                                                    h_neigh, E);
    } else {
        hipMemsetAsync(d_ws, 0, hn_b, stream);
        edge_kernel<0><<<eblocks, 256, 0, stream>>>(node_feat, coord, edge_feat,
                                                    src, dst, nullptr,
                                                    W_e1, b_e1, W_e2, b_e2,
                                                    h_neigh, E);
    }

    const int nblocks = (N + TN - 1) / TN;
    node_kernel<<<nblocks, 256, 0, stream>>>(node_feat, h_neigh,
                                             W_n1, b_n1, W_n2, b_n2,
                                             (float*)d_out, N);
}

// Round 5
// 646.803 us; speedup vs baseline: 1.6547x; 1.1758x over previous
//
#include <hip/hip_runtime.h>

#define D 64
#define H 64
#define EFD 16
#define MS 68    // LDS tile row stride (floats), 16B-aligned
#define TE 128   // edges per block
#define TN 128   // nodes per block
#define DPB 16   // dsts per block (edge_kernel2)

__device__ __forceinline__ float silu(float x) {
    return x / (1.0f + __expf(-x));
}

// acc[j] += sum_kk a[kk] * b[kk][j], b stored as float4 bf[4] (bp[kk*4+j])
#define GEMM_STEP(acc_, a_, bf_) do { \
    const float* bp_ = (const float*)(bf_); \
    acc_[0] += (a_).x*bp_[0] + (a_).y*bp_[4] + (a_).z*bp_[8]  + (a_).w*bp_[12]; \
    acc_[1] += (a_).x*bp_[1] + (a_).y*bp_[5] + (a_).z*bp_[9]  + (a_).w*bp_[13]; \
    acc_[2] += (a_).x*bp_[2] + (a_).y*bp_[6] + (a_).z*bp_[10] + (a_).w*bp_[14]; \
    acc_[3] += (a_).x*bp_[3] + (a_).y*bp_[7] + (a_).z*bp_[11] + (a_).w*bp_[15]; \
} while (0)

// one 16-k4-step partial GEMM over smem rows [8eg..], W rows [wrow0..wrow0+63]
#define PGEMM64(acc_, Wp_, wrow0_, eg_, hg_, smem_) do { \
    for (int k4 = 0; k4 < 16; k4++) { \
        float4 bf_[4]; \
        _Pragma("unroll") \
        for (int kk = 0; kk < 4; kk++) \
            bf_[kk] = *(const float4*)&(Wp_)[(size_t)((wrow0_) + 4*k4 + kk) * H + 4*(hg_)]; \
        _Pragma("unroll") \
        for (int i = 0; i < 8; i++) { \
            float4 a_ = *(const float4*)&(smem_)[(8*(eg_) + i) * MS + 4*k4]; \
            GEMM_STEP(acc_[i], a_, bf_); \
        } \
    } \
} while (0)

// ---------------- sort-by-dst construction ----------------

__global__ __launch_bounds__(256) void hist_kernel(
    const int* __restrict__ dst, int* __restrict__ deg, int E)
{
    int e = blockIdx.x * 256 + threadIdx.x;
    if (e < E) atomicAdd(&deg[dst[e]], 1);
}

__global__ __launch_bounds__(1024, 1) void scan_kernel(
    const int* __restrict__ deg, int* __restrict__ cursor, int N)
{
    __shared__ int wsums[16];
    __shared__ int carry_s;
    const int tid = threadIdx.x;
    const int lane = tid & 63, wid = tid >> 6;
    if (tid == 0) carry_s = 0;
    __syncthreads();
    for (int base = 0; base < N; base += 1024) {
        int idx = base + tid;
        int v = (idx < N) ? deg[idx] : 0;
        int x = v;
        #pragma unroll
        for (int off = 1; off < 64; off <<= 1) {
            int y = __shfl_up(x, off, 64);
            if (lane >= off) x += y;
        }
        if (lane == 63) wsums[wid] = x;
        __syncthreads();
        if (wid == 0) {
            int ws = (lane < 16) ? wsums[lane] : 0;
            #pragma unroll
            for (int off = 1; off < 16; off <<= 1) {
                int y = __shfl_up(ws, off, 64);
                if (lane >= off) ws += y;
            }
            if (lane < 16) wsums[lane] = ws;   // inclusive scan of wave sums
        }
        __syncthreads();
        int wprefix = (wid > 0) ? wsums[wid - 1] : 0;
        int excl = carry_s + wprefix + x - v;
        if (idx < N) cursor[idx] = excl;
        __syncthreads();
        if (tid == 0) carry_s += wsums[15];
        __syncthreads();
    }
}

// writes eidx + pre-gathered srcs/dsts in sorted order
__global__ __launch_bounds__(256) void build2_kernel(
    const int* __restrict__ dst, const int* __restrict__ src,
    int* __restrict__ cursor,
    int* __restrict__ eidx, int* __restrict__ srcs, int* __restrict__ dsts,
    int E)
{
    int e = blockIdx.x * 256 + threadIdx.x;
    if (e < E) {
        int d2 = dst[e];
        int pos = atomicAdd(&cursor[d2], 1);
        eidx[pos] = e;
        srcs[pos] = src[e];
        dsts[pos] = d2;
    }
}

__global__ __launch_bounds__(256) void build_kernel(
    const int* __restrict__ dst, int* __restrict__ cursor,
    int* __restrict__ eidx, int E)
{
    int e = blockIdx.x * 256 + threadIdx.x;
    if (e < E) {
        int pos = atomicAdd(&cursor[dst[e]], 1);
        eidx[pos] = e;
    }
}

// ---------------- Pa/Pb precompute ----------------
// Pa = node_feat @ W_e1[0:64]   + b_e1
// Pb = node_feat @ W_e1[64:128]

__global__ __launch_bounds__(256, 4) void pre_kernel(
    const float* __restrict__ node_feat,
    const float* __restrict__ W_e1, const float* __restrict__ b_e1,
    float* __restrict__ Pa, float* __restrict__ Pb, int N)
{
    __shared__ float smem[TN * MS];
    const int tid = threadIdx.x;
    const int nbase = blockIdx.x * TN;
    const int ng = tid >> 4, hg = tid & 15, k = tid & 63, no = tid >> 6;

    #pragma unroll
    for (int t = 0; t < 32; t++) {
        int gn = nbase + no + 4*t;
        int cg = (gn < N) ? gn : (N - 1);
        smem[(no + 4*t) * MS + k] = node_feat[(size_t)cg * D + k];
    }
    __syncthreads();

    float accA[8][4], accB[8][4];
    {
        float4 b0 = *(const float4*)&b_e1[4*hg];
        #pragma unroll
        for (int i = 0; i < 8; i++) {
            accA[i][0]=b0.x; accA[i][1]=b0.y; accA[i][2]=b0.z; accA[i][3]=b0.w;
            accB[i][0]=0.f;  accB[i][1]=0.f;  accB[i][2]=0.f;  accB[i][3]=0.f;
        }
    }
    PGEMM64(accA, W_e1, 0,  ng, hg, smem);
    PGEMM64(accB, W_e1, 64, ng, hg, smem);

    #pragma unroll
    for (int i = 0; i < 8; i++) {
        int gn = nbase + 8*ng + i;
        if (gn < N) {
            float4 a; a.x=accA[i][0]; a.y=accA[i][1]; a.z=accA[i][2]; a.w=accA[i][3];
            float4 b; b.x=accB[i][0]; b.y=accB[i][1]; b.z=accB[i][2]; b.w=accB[i][3];
            *(float4*)&Pa[(size_t)gn * H + 4*hg] = a;
            *(float4*)&Pb[(size_t)gn * H + 4*hg] = b;
        }
    }
}

// ---------------- edge kernel v2: dst-owned blocks, no global atomics ----------------

__global__ __launch_bounds__(256, 4) void edge_kernel2(
    const float* __restrict__ Pa, const float* __restrict__ Pb,
    const float* __restrict__ coord,
    const float* __restrict__ edge_feat,
    const int* __restrict__ eidx, const int* __restrict__ srcs,
    const int* __restrict__ dsts,
    const int* __restrict__ cursor_end, const int* __restrict__ deg,
    const float* __restrict__ W_e1,
    const float* __restrict__ W_e2, const float* __restrict__ b_e2,
    float* __restrict__ h_neigh, int N)
{
    __shared__ float smem[TE * MS];          // ef tile (cols 0..16) then m tile (cols 0..63)
    __shared__ float hacc[DPB * H];          // per-dst accumulator
    __shared__ int ssrc[TE], sdlo[TE], seid[TE];

    const int tid = threadIdx.x;
    const int dst0 = blockIdx.x * DPB;
    const int dlast = min(dst0 + DPB, N) - 1;
    const int rs = cursor_end[dst0] - deg[dst0];
    const int re = cursor_end[dlast];

    for (int i = tid; i < DPB * H; i += 256) hacc[i] = 0.f;

    const int eg = tid >> 4;   // 0..15 -> 8 edge rows each
    const int hg = tid & 15;   // 0..15 -> 4 out channels each

    for (int base = rs; base < re; base += TE) {
        const int cnt = min(re - base, TE);
        __syncthreads();   // (a) prev-iter smem reads + hacc init visible

        if (tid < TE) {
            int e = 0, s = 0, dl = -1;
            float radial = 0.f;
            if (tid < cnt) {
                int p = base + tid;
                e = eidx[p]; s = srcs[p];
                int d2 = dsts[p]; dl = d2 - dst0;
                float dx = coord[s*3+0] - coord[d2*3+0];
                float dy = coord[s*3+1] - coord[d2*3+1];
                float dz = coord[s*3+2] - coord[d2*3+2];
                radial = dx*dx + dy*dy + dz*dz;
            }
            ssrc[tid] = s; sdlo[tid] = dl; seid[tid] = e;
            smem[tid * MS + 0] = radial;
        }
        __syncthreads();   // (b) idx arrays + radial ready

        // stage edge_feat into cols 1..16
        {
            const int k2 = tid & 15, e2 = tid >> 4;
            #pragma unroll
            for (int t = 0; t < 8; t++) {
                int r = e2 + 16*t;
                float v = (sdlo[r] >= 0) ? edge_feat[(size_t)seid[r] * EFD + k2] : 0.f;
                smem[r * MS + 1 + k2] = v;
            }
        }

        // acc = Pa[src] + Pb[dst]  (bias folded into Pa)
        float acc[8][4];
        #pragma unroll
        for (int i = 0; i < 8; i++) {
            int r = 8*eg + i;
            int s = ssrc[r];
            int dl = sdlo[r];
            int drow = (dl >= 0) ? (dst0 + dl) : 0;
            float4 pa = *(const float4*)&Pa[(size_t)s * H + 4*hg];
            float4 pb = *(const float4*)&Pb[(size_t)drow * H + 4*hg];
            acc[i][0] = pa.x + pb.x; acc[i][1] = pa.y + pb.y;
            acc[i][2] = pa.z + pb.z; acc[i][3] = pa.w + pb.w;
        }
        __syncthreads();   // (c) ef tile staged

        // [radial|ef] (17 cols) @ W_e1 rows 128..144
        for (int k4 = 0; k4 < 4; k4++) {
            float4 bf[4];
            #pragma unroll
            for (int kk = 0; kk < 4; kk++)
                bf[kk] = *(const float4*)&W_e1[(size_t)(128 + 4*k4 + kk) * H + 4*hg];
            #pragma unroll
            for (int i = 0; i < 8; i++) {
                float4 a = *(const float4*)&smem[(8*eg + i) * MS + 4*k4];
                GEMM_STEP(acc[i], a, bf);
            }
        }
        {
            float4 b = *(const float4*)&W_e1[(size_t)144 * H + 4*hg];
            #pragma unroll
            for (int i = 0; i < 8; i++) {
                float a = smem[(8*eg+i)*MS + 16];
                acc[i][0] += a*b.x; acc[i][1] += a*b.y; acc[i][2] += a*b.z; acc[i][3] += a*b.w;
            }
        }
        __syncthreads();   // (d) ef reads done before m overwrite

        #pragma unroll
        for (int i = 0; i < 8; i++) {
            float4 mv;
            mv.x = silu(acc[i][0]); mv.y = silu(acc[i][1]);
            mv.z = silu(acc[i][2]); mv.w = silu(acc[i][3]);
            *(float4*)&smem[(8*eg+i)*MS + 4*hg] = mv;
        }
        __syncthreads();   // (e) m ready

        float acc2[8][4];
        {
            float4 b0 = *(const float4*)&b_e2[4*hg];
            #pragma unroll
            for (int i = 0; i < 8; i++) {
                acc2[i][0]=b0.x; acc2[i][1]=b0.y; acc2[i][2]=b0.z; acc2[i][3]=b0.w;
            }
        }
        PGEMM64(acc2, W_e2, 0, eg, hg, smem);

        // run-combine within this thread's 8 rows, LDS-atomic per run
        float rx=0.f, ry=0.f, rz=0.f, rw=0.f;
        int cur = -1;
        #pragma unroll
        for (int i = 0; i < 8; i++) {
            int r = 8*eg + i;
            int dl = sdlo[r];
            if (dl < 0) continue;
            float vx = silu(acc2[i][0]), vy = silu(acc2[i][1]);
            float vz = silu(acc2[i][2]), vw = silu(acc2[i][3]);
            if (dl != cur) {
                if (cur >= 0) {
                    float* hp = &hacc[cur * H + 4*hg];
                    atomicAdd(&hp[0], rx); atomicAdd(&hp[1], ry);
                    atomicAdd(&hp[2], rz); atomicAdd(&hp[3], rw);
                }
                cur = dl; rx = vx; ry = vy; rz = vz; rw = vw;
            } else {
                rx += vx; ry += vy; rz += vz; rw += vw;
            }
        }
        if (cur >= 0) {
            float* hp = &hacc[cur * H + 4*hg];
            atomicAdd(&hp[0], rx); atomicAdd(&hp[1], ry);
            atomicAdd(&hp[2], rz); atomicAdd(&hp[3], rw);
        }
    }

    __syncthreads();   // (f) all accumulation done
    {
        const int dloc = tid >> 4;          // 0..15
        const int ch = 4 * (tid & 15);
        int gd = dst0 + dloc;
        if (gd < N) {
            float4 v = *(const float4*)&hacc[dloc * H + ch];
            *(float4*)&h_neigh[(size_t)gd * H + ch] = v;
        }
    }
}

// ---------------- legacy edge kernel (fallback when ws is small) ----------------

template <int MODE>
__global__ __launch_bounds__(256, 4) void edge_kernel(
    const float* __restrict__ node_feat,
    const float* __restrict__ coord,
    const float* __restrict__ edge_feat,
    const int* __restrict__ src,
    const int* __restrict__ dst,
    const int* __restrict__ eidx_g,
    const float* __restrict__ W_e1, const float* __restrict__ b_e1,
    const float* __restrict__ W_e2, const float* __restrict__ b_e2,
    float* __restrict__ h_neigh,
    int E)
{
    __shared__ float smem[TE * MS];
    __shared__ int ssrc[TE];
    __shared__ int sdst[TE];
    __shared__ int seid[TE];

    const int tid = threadIdx.x;
    const int ebase = blockIdx.x * TE;

    float radial = 0.f;
    if (tid < TE) {
        int p = ebase + tid;
        int e = p, s = 0, d2 = -1;
        if (p < E) {
            if (MODE == 1) e = eidx_g[p];
            s = src[e];
            d2 = dst[e];
        }
        ssrc[tid] = s;
        sdst[tid] = d2;
        seid[tid] = e;
        if (d2 >= 0) {
            float dx = coord[s*3+0] - coord[d2*3+0];
            float dy = coord[s*3+1] - coord[d2*3+1];
            float dz = coord[s*3+2] - coord[d2*3+2];
            radial = dx*dx + dy*dy + dz*dz;
        }
    }
    __syncthreads();

    const int eg = tid >> 4;
    const int hg = tid & 15;
    const int k  = tid & 63;
    const int eo = tid >> 6;

    float acc[8][4];
    {
        float4 b0 = *(const float4*)&b_e1[4*hg];
        #pragma unroll
        for (int i = 0; i < 8; i++) {
            acc[i][0]=b0.x; acc[i][1]=b0.y; acc[i][2]=b0.z; acc[i][3]=b0.w;
        }
    }

    float rA[32];
    #pragma unroll
    for (int t = 0; t < 32; t++)
        rA[t] = node_feat[(size_t)ssrc[eo + 4*t] * D + k];
    #pragma unroll
    for (int t = 0; t < 32; t++)
        smem[(eo + 4*t) * MS + k] = rA[t];
    __syncthreads();

    float rB[32];
    #pragma unroll
    for (int t = 0; t < 32; t++) {
        int row = sdst[eo + 4*t];
        row = row < 0 ? 0 : row;
        rB[t] = node_feat[(size_t)row * D + k];
    }
    PGEMM64(acc, W_e1, 0, eg, hg, smem);
    __syncthreads();

    #pragma unroll
    for (int t = 0; t < 32; t++)
        smem[(eo + 4*t) * MS + k] = rB[t];
    __syncthreads();

    float rC[8];
    {
        const int k2 = tid & 15, e2 = tid >> 4;
        #pragma unroll
        for (int t = 0; t < 8; t++) {
            int r = e2 + 16*t;
            rC[t] = (ebase + r < E) ? edge_feat[(size_t)seid[r] * EFD + k2] : 0.f;
        }
    }
    PGEMM64(acc, W_e1, 64, eg, hg, smem);
    __syncthreads();

    {
        const int k2 = tid & 15, e2 = tid >> 4;
        #pragma unroll
        for (int t = 0; t < 8; t++)
            smem[(e2 + 16*t) * MS + 1 + k2] = rC[t];
        if (tid < TE) smem[tid * MS + 0] = radial;
    }
    __syncthreads();

    for (int k4 = 0; k4 < 4; k4++) {
        float4 bf[4];
        #pragma unroll
        for (int kk = 0; kk < 4; kk++)
            bf[kk] = *(const float4*)&W_e1[(size_t)(128 + 4*k4 + kk) * H + 4*hg];
        #pragma unroll
        for (int i = 0; i < 8; i++) {
            float4 a = *(const float4*)&smem[(8*eg + i) * MS + 4*k4];
            GEMM_STEP(acc[i], a, bf);
        }
    }
    {
        float4 b = *(const float4*)&W_e1[(size_t)144 * H + 4*hg];
        #pragma unroll
        for (int i = 0; i < 8; i++) {
            float a = smem[(8*eg+i)*MS + 16];
            acc[i][0] += a*b.x; acc[i][1] += a*b.y; acc[i][2] += a*b.z; acc[i][3] += a*b.w;
        }
    }
    __syncthreads();

    #pragma unroll
    for (int i = 0; i < 8; i++) {
        float4 mv;
        mv.x = silu(acc[i][0]); mv.y = silu(acc[i][1]);
        mv.z = silu(acc[i][2]); mv.w = silu(acc[i][3]);
        *(float4*)&smem[(8*eg+i)*MS + 4*hg] = mv;
    }
    __syncthreads();

    float acc2[8][4];
    {
        float4 b0 = *(const float4*)&b_e2[4*hg];
        #pragma unroll
        for (int i = 0; i < 8; i++) {
            acc2[i][0]=b0.x; acc2[i][1]=b0.y; acc2[i][2]=b0.z; acc2[i][3]=b0.w;
        }
    }
    PGEMM64(acc2, W_e2, 0, eg, hg, smem);

    if (MODE == 0) {
        #pragma unroll
        for (int i = 0; i < 8; i++) {
            int r = 8*eg + i;
            int dr = sdst[r];
            if (dr >= 0) {
                float* hp = &h_neigh[(size_t)dr * H + 4*hg];
                atomicAdd(&hp[0], silu(acc2[i][0]));
                atomicAdd(&hp[1], silu(acc2[i][1]));
                atomicAdd(&hp[2], silu(acc2[i][2]));
                atomicAdd(&hp[3], silu(acc2[i][3]));
            }
        }
    } else {
        __syncthreads();
        #pragma unroll
        for (int i = 0; i < 8; i++) {
            float4 mv;
            mv.x = silu(acc2[i][0]); mv.y = silu(acc2[i][1]);
            mv.z = silu(acc2[i][2]); mv.w = silu(acc2[i][3]);
            *(float4*)&smem[(8*eg+i)*MS + 4*hg] = mv;
        }
        __syncthreads();

        int emaxt = E - ebase; if (emaxt > TE) emaxt = TE;
        #pragma unroll 1
        for (int i = 0; i < 8; i++) {
            int r = 8*eg + i;
            if (r >= emaxt) break;
            int dr = sdst[r];
            if (dr < 0) continue;
            if (r > 0 && sdst[r-1] == dr) continue;
            float4 s = *(const float4*)&smem[r*MS + 4*hg];
            int rr = r + 1;
            while (rr < emaxt && sdst[rr] == dr) {
                const float* mp = &smem[rr*MS + 4*hg];
                s.x += mp[0]; s.y += mp[1]; s.z += mp[2]; s.w += mp[3];
                rr++;
            }
            float* hp = &h_neigh[(size_t)dr * H + 4*hg];
            atomicAdd(&hp[0], s.x); atomicAdd(&hp[1], s.y);
            atomicAdd(&hp[2], s.z); atomicAdd(&hp[3], s.w);
        }
    }
}

// ---------------- node kernel ----------------

__global__ __launch_bounds__(256, 4) void node_kernel(
    const float* __restrict__ node_feat,
    const float* __restrict__ h_neigh,
    const float* __restrict__ W_n1, const float* __restrict__ b_n1,
    const float* __restrict__ W_n2, const float* __restrict__ b_n2,
    float* __restrict__ out, int N)
{
    __shared__ float smem[TN * MS];

    const int tid = threadIdx.x;
    const int nbase = blockIdx.x * TN;

    const int ng = tid >> 4;
    const int hg = tid & 15;
    const int k  = tid & 63;
    const int no = tid >> 6;

    float acc[8][4];
    {
        float4 b0 = *(const float4*)&b_n1[4*hg];
        #pragma unroll
        for (int i = 0; i < 8; i++) {
            acc[i][0]=b0.x; acc[i][1]=b0.y; acc[i][2]=b0.z; acc[i][3]=b0.w;
        }
    }

    float rA[32];
    #pragma unroll
    for (int t = 0; t < 32; t++) {
        int gn = nbase + no + 4*t;
        int cg = (gn < N) ? gn : (N - 1);
        rA[t] = node_feat[(size_t)cg * D + k];
    }
    #pragma unroll
    for (int t = 0; t < 32; t++)
        smem[(no + 4*t) * MS + k] = rA[t];
    __syncthreads();

    float rB[32];
    #pragma unroll
    for (int t = 0; t < 32; t++) {
        int gn = nbase + no + 4*t;
        int cg = (gn < N) ? gn : (N - 1);
        rB[t] = h_neigh[(size_t)cg * H + k];
    }
    PGEMM64(acc, W_n1, 0, ng, hg, smem);
    __syncthreads();

    #pragma unroll
    for (int t = 0; t < 32; t++)
        smem[(no + 4*t) * MS + k] = rB[t];
    __syncthreads();

    PGEMM64(acc, W_n1, 64, ng, hg, smem);
    __syncthreads();

    #pragma unroll
    for (int i = 0; i < 8; i++) {
        float4 mv;
        mv.x = silu(acc[i][0]); mv.y = silu(acc[i][1]);
        mv.z = silu(acc[i][2]); mv.w = silu(acc[i][3]);
        *(float4*)&smem[(8*ng+i)*MS + 4*hg] = mv;
    }
    __syncthreads();

    float acc2[8][4];
    {
        float4 b0 = *(const float4*)&b_n2[4*hg];
        #pragma unroll
        for (int i = 0; i < 8; i++) {
            acc2[i][0]=b0.x; acc2[i][1]=b0.y; acc2[i][2]=b0.z; acc2[i][3]=b0.w;
        }
    }
    PGEMM64(acc2, W_n2, 0, ng, hg, smem);

    #pragma unroll
    for (int i = 0; i < 8; i++) {
        int gn = nbase + 8*ng + i;
        if (gn < N) {
            float4 ov;
            ov.x = acc2[i][0]; ov.y = acc2[i][1]; ov.z = acc2[i][2]; ov.w = acc2[i][3];
            *(float4*)&out[(size_t)gn * D + 4*hg] = ov;
        }
    }
}

extern "C" void kernel_launch(void* const* d_in, const int* in_sizes, int n_in,
                              void* d_out, int out_size, void* d_ws, size_t ws_size,
                              hipStream_t stream)
{
    const float* node_feat = (const float*)d_in[0];
    const float* coord     = (const float*)d_in[1];
    const float* edge_feat = (const float*)d_in[2];
    const int*   src       = (const int*)d_in[3];
    const int*   dst       = (const int*)d_in[4];
    const float* W_e1 = (const float*)d_in[5];
    const float* b_e1 = (const float*)d_in[6];
    const float* W_e2 = (const float*)d_in[7];
    const float* b_e2 = (const float*)d_in[8];
    const float* W_n1 = (const float*)d_in[9];
    const float* b_n1 = (const float*)d_in[10];
    const float* W_n2 = (const float*)d_in[11];
    const float* b_n2 = (const float*)d_in[12];

    const int N = in_sizes[0] / D;
    const int E = in_sizes[3];

    const size_t hn_b   = (size_t)N * H * sizeof(float);
    const size_t n_i    = (size_t)N * sizeof(int);
    const size_t e_i    = (size_t)E * sizeof(int);
    const size_t p_b    = (size_t)N * H * sizeof(float);

    // MODE2 layout: h_neigh | deg | cursor | eidx | srcs | dsts | Pa | Pb
    const size_t need2 = hn_b + 2*n_i + 3*e_i + 2*p_b;
    // MODE1 layout: h_neigh | deg | cursor | eidx
    const size_t need1 = hn_b + 2*n_i + e_i;

    float* h_neigh = (float*)d_ws;
    const int eblocks = (E + TE - 1) / TE;

    if (ws_size >= need2) {
        char* p = (char*)d_ws + hn_b;
        int* deg    = (int*)p;              p += n_i;
        int* cursor = (int*)p;              p += n_i;
        int* eidx   = (int*)p;              p += e_i;
        int* srcs   = (int*)p;              p += e_i;
        int* dsts   = (int*)p;              p += e_i;
        float* Pa   = (float*)p;            p += p_b;
        float* Pb   = (float*)p;

        hipMemsetAsync(deg, 0, n_i, stream);
        hist_kernel<<<(E + 255) / 256, 256, 0, stream>>>(dst, deg, E);
        scan_kernel<<<1, 1024, 0, stream>>>(deg, cursor, N);
        build2_kernel<<<(E + 255) / 256, 256, 0, stream>>>(dst, src, cursor,
                                                           eidx, srcs, dsts, E);
        pre_kernel<<<(N + TN - 1) / TN, 256, 0, stream>>>(node_feat, W_e1, b_e1,
                                                          Pa, Pb, N);
        const int dblocks = (N + DPB - 1) / DPB;
        edge_kernel2<<<dblocks, 256, 0, stream>>>(Pa, Pb, coord, edge_feat,
                                                  eidx, srcs, dsts, cursor, deg,
                                                  W_e1, W_e2, b_e2, h_neigh, N);
    } else if (ws_size >= need1) {
        int* deg    = (int*)((char*)d_ws + hn_b);
        int* cursor = (int*)((char*)deg + n_i);
        int* eidx   = (int*)((char*)cursor + n_i);
        hipMemsetAsync(d_ws, 0, hn_b + n_i, stream);
        hist_kernel<<<(E + 255) / 256, 256, 0, stream>>>(dst, deg, E);
        scan_kernel<<<1, 1024, 0, stream>>>(deg, cursor, N);
        build_kernel<<<(E + 255) / 256, 256, 0, stream>>>(dst, cursor, eidx, E);
        edge_kernel<1><<<eblocks, 256, 0, stream>>>(node_feat, coord, edge_feat,
                                                    src, dst, eidx,
                                                    W_e1, b_e1, W_e2, b_e2,
                                                    h_neigh, E);
    } else {
        hipMemsetAsync(d_ws, 0, hn_b, stream);
        edge_kernel<0><<<eblocks, 256, 0, stream>>>(node_feat, coord, edge_feat,
                                                    src, dst, nullptr,
                                                    W_e1, b_e1, W_e2, b_e2,
                                                    h_neigh, E);
    }

    const int nblocks = (N + TN - 1) / TN;
    node_kernel<<<nblocks, 256, 0, stream>>>(node_feat, h_neigh,
                                             W_n1, b_n1, W_n2, b_n2,
                                             (float*)d_out, N);
}

// Round 6
// 610.364 us; speedup vs baseline: 1.7535x; 1.0597x over previous
//
#include <hip/hip_runtime.h>

#define D 64
#define H 64
#define EFD 16
#define MS 68    // LDS m-tile row stride (floats)
#define TE 128   // edges per tile
#define TN 128   // nodes per block
#define DPB 16   // dsts per block (edge kernels 2/3)
#define REFW 20  // packed [ef(16)|radial|pad3] row stride (floats), 80B

__device__ __forceinline__ float silu(float x) {
    return x / (1.0f + __expf(-x));
}

#define GEMM_STEP(acc_, a_, bf_) do { \
    const float* bp_ = (const float*)(bf_); \
    acc_[0] += (a_).x*bp_[0] + (a_).y*bp_[4] + (a_).z*bp_[8]  + (a_).w*bp_[12]; \
    acc_[1] += (a_).x*bp_[1] + (a_).y*bp_[5] + (a_).z*bp_[9]  + (a_).w*bp_[13]; \
    acc_[2] += (a_).x*bp_[2] + (a_).y*bp_[6] + (a_).z*bp_[10] + (a_).w*bp_[14]; \
    acc_[3] += (a_).x*bp_[3] + (a_).y*bp_[7] + (a_).z*bp_[11] + (a_).w*bp_[15]; \
} while (0)

#define PGEMM64(acc_, Wp_, wrow0_, eg_, hg_, smem_) do { \
    for (int k4 = 0; k4 < 16; k4++) { \
        float4 bf_[4]; \
        _Pragma("unroll") \
        for (int kk = 0; kk < 4; kk++) \
            bf_[kk] = *(const float4*)&(Wp_)[(size_t)((wrow0_) + 4*k4 + kk) * H + 4*(hg_)]; \
        _Pragma("unroll") \
        for (int i = 0; i < 8; i++) { \
            float4 a_ = *(const float4*)&(smem_)[(8*(eg_) + i) * MS + 4*k4]; \
            GEMM_STEP(acc_[i], a_, bf_); \
        } \
    } \
} while (0)

// ---------------- histogram ----------------

__global__ __launch_bounds__(256) void hist_kernel(
    const int* __restrict__ dst, int* __restrict__ deg, int E)
{
    int e = blockIdx.x * 256 + threadIdx.x;
    if (e < E) atomicAdd(&deg[dst[e]], 1);
}

// ---------------- 3-phase multi-block exclusive scan ----------------

__global__ __launch_bounds__(256) void scanA_kernel(
    const int* __restrict__ deg, int* __restrict__ part, int N)
{
    __shared__ int tmp[256];
    const int tid = threadIdx.x;
    int idx = blockIdx.x * 256 + tid;
    tmp[tid] = (idx < N) ? deg[idx] : 0;
    __syncthreads();
    for (int off = 128; off > 0; off >>= 1) {
        if (tid < off) tmp[tid] += tmp[tid + off];
        __syncthreads();
    }
    if (tid == 0) part[blockIdx.x] = tmp[0];
}

__global__ __launch_bounds__(256, 1) void scanB_kernel(
    int* __restrict__ part, int nparts)
{
    __shared__ int tmp[256];
    __shared__ int carry_s;
    const int tid = threadIdx.x;
    if (tid == 0) carry_s = 0;
    __syncthreads();
    for (int base = 0; base < nparts; base += 256) {
        int idx = base + tid;
        int v = (idx < nparts) ? part[idx] : 0;
        tmp[tid] = v;
        __syncthreads();
        #pragma unroll
        for (int off = 1; off < 256; off <<= 1) {
            int t = (tid >= off) ? tmp[tid - off] : 0;
            __syncthreads();
            tmp[tid] += t;
            __syncthreads();
        }
        int incl = tmp[tid];
        int tot = tmp[255];
        if (idx < nparts) part[idx] = carry_s + incl - v;  // exclusive
        __syncthreads();
        if (tid == 0) carry_s += tot;
        __syncthreads();
    }
}

__global__ __launch_bounds__(256) void scanC_kernel(
    const int* __restrict__ deg, const int* __restrict__ part,
    int* __restrict__ cursor, int N)
{
    __shared__ int tmp[256];
    const int tid = threadIdx.x;
    int idx = blockIdx.x * 256 + tid;
    int v = (idx < N) ? deg[idx] : 0;
    tmp[tid] = v;
    __syncthreads();
    #pragma unroll
    for (int off = 1; off < 256; off <<= 1) {
        int t = (tid >= off) ? tmp[tid - off] : 0;
        __syncthreads();
        tmp[tid] += t;
        __syncthreads();
    }
    if (idx < N) cursor[idx] = part[blockIdx.x] + tmp[tid] - v;
}

// ---------------- build: sort all per-edge data by dst ----------------
// refr row layout: [ef0..ef15 | radial | pad3]

__global__ __launch_bounds__(256) void build3_kernel(
    const int* __restrict__ dst, const int* __restrict__ src,
    const float* __restrict__ coord, const float* __restrict__ edge_feat,
    int* __restrict__ cursor,
    int* __restrict__ srcs, int* __restrict__ dsts, float* __restrict__ refr,
    int E)
{
    int e = blockIdx.x * 256 + threadIdx.x;
    if (e >= E) return;
    int d2 = dst[e];
    int s = src[e];
    int pos = atomicAdd(&cursor[d2], 1);
    srcs[pos] = s;
    dsts[pos] = d2;
    float dx = coord[s*3+0] - coord[d2*3+0];
    float dy = coord[s*3+1] - coord[d2*3+1];
    float dz = coord[s*3+2] - coord[d2*3+2];
    float* rr = &refr[(size_t)pos * REFW];
    const float4* ef = (const float4*)&edge_feat[(size_t)e * EFD];
    *(float4*)&rr[0]  = ef[0];
    *(float4*)&rr[4]  = ef[1];
    *(float4*)&rr[8]  = ef[2];
    *(float4*)&rr[12] = ef[3];
    rr[16] = dx*dx + dy*dy + dz*dz;
}

// legacy build (tier 2)
__global__ __launch_bounds__(256) void build2_kernel(
    const int* __restrict__ dst, const int* __restrict__ src,
    int* __restrict__ cursor,
    int* __restrict__ eidx, int* __restrict__ srcs, int* __restrict__ dsts,
    int E)
{
    int e = blockIdx.x * 256 + threadIdx.x;
    if (e < E) {
        int d2 = dst[e];
        int pos = atomicAdd(&cursor[d2], 1);
        eidx[pos] = e;
        srcs[pos] = src[e];
        dsts[pos] = d2;
    }
}

// ---------------- Pa/Pb precompute ----------------

__global__ __launch_bounds__(256, 4) void pre_kernel(
    const float* __restrict__ node_feat,
    const float* __restrict__ W_e1, const float* __restrict__ b_e1,
    float* __restrict__ Pa, float* __restrict__ Pb, int N)
{
    __shared__ float smem[TN * MS];
    const int tid = threadIdx.x;
    const int nbase = blockIdx.x * TN;
    const int ng = tid >> 4, hg = tid & 15, k = tid & 63, no = tid >> 6;

    #pragma unroll
    for (int t = 0; t < 32; t++) {
        int gn = nbase + no + 4*t;
        int cg = (gn < N) ? gn : (N - 1);
        smem[(no + 4*t) * MS + k] = node_feat[(size_t)cg * D + k];
    }
    __syncthreads();

    float accA[8][4], accB[8][4];
    {
        float4 b0 = *(const float4*)&b_e1[4*hg];
        #pragma unroll
        for (int i = 0; i < 8; i++) {
            accA[i][0]=b0.x; accA[i][1]=b0.y; accA[i][2]=b0.z; accA[i][3]=b0.w;
            accB[i][0]=0.f;  accB[i][1]=0.f;  accB[i][2]=0.f;  accB[i][3]=0.f;
        }
    }
    PGEMM64(accA, W_e1, 0,  ng, hg, smem);
    PGEMM64(accB, W_e1, 64, ng, hg, smem);

    #pragma unroll
    for (int i = 0; i < 8; i++) {
        int gn = nbase + 8*ng + i;
        if (gn < N) {
            float4 a; a.x=accA[i][0]; a.y=accA[i][1]; a.z=accA[i][2]; a.w=accA[i][3];
            float4 b; b.x=accB[i][0]; b.y=accB[i][1]; b.z=accB[i][2]; b.w=accB[i][3];
            *(float4*)&Pa[(size_t)gn * H + 4*hg] = a;
            *(float4*)&Pb[(size_t)gn * H + 4*hg] = b;
        }
    }
}

// ---------------- edge kernel v3: pipelined, 2 barriers/tile ----------------

__global__ __launch_bounds__(256, 3) void edge_kernel3(
    const float* __restrict__ Pa, const float* __restrict__ Pb,
    const int* __restrict__ srcs, const int* __restrict__ dsts,
    const float* __restrict__ refr,
    const int* __restrict__ cursor_end, const int* __restrict__ deg,
    const float* __restrict__ W_e1,
    const float* __restrict__ W_e2, const float* __restrict__ b_e2,
    float* __restrict__ h_neigh, int N)
{
    __shared__ float smem[TE * MS];      // m tile
    __shared__ float hacc[DPB * H];      // per-dst accumulator

    const int tid = threadIdx.x;
    const int dst0 = blockIdx.x * DPB;
    const int dlast = min(dst0 + DPB, N) - 1;
    const int rs = cursor_end[dst0] - deg[dst0];
    const int re = cursor_end[dlast];

    for (int i = tid; i < DPB * H; i += 256) hacc[i] = 0.f;

    const int eg = tid >> 4, hg = tid & 15;

    float acc[8][4];
    int dl[8];

    // load one tile's Pa+Pb (bias folded into Pa) and local-dst ids into regs
    #define LOAD_TILE(base_, acc_, dl_) do { \
        _Pragma("unroll") \
        for (int i_ = 0; i_ < 8; i_++) { \
            int p_ = (base_) + 8*eg + i_; \
            bool val_ = (p_ < re); \
            int pp_ = val_ ? p_ : (re - 1); \
            int s_ = srcs[pp_]; \
            int d2_ = dsts[pp_]; \
            float4 pa_ = *(const float4*)&Pa[(size_t)s_ * H + 4*hg]; \
            float4 pb_ = *(const float4*)&Pb[(size_t)d2_ * H + 4*hg]; \
            acc_[i_][0] = pa_.x + pb_.x; acc_[i_][1] = pa_.y + pb_.y; \
            acc_[i_][2] = pa_.z + pb_.z; acc_[i_][3] = pa_.w + pb_.w; \
            dl_[i_] = val_ ? (d2_ - dst0) : -1; \
        } \
    } while (0)

    if (re > rs) LOAD_TILE(rs, acc, dl);

    for (int base = rs; base < re; base += TE) {
        // ---- K=17 tail GEMM: A rows straight from refr (L1-hot, 16x reuse) ----
        // cols 0..15 = ef  <-> W_e1 rows 129..144 ; col 16 = radial <-> row 128
        for (int k4 = 0; k4 < 4; k4++) {
            float4 bf[4];
            #pragma unroll
            for (int kk = 0; kk < 4; kk++)
                bf[kk] = *(const float4*)&W_e1[(size_t)(129 + 4*k4 + kk) * H + 4*hg];
            #pragma unroll
            for (int i = 0; i < 8; i++) {
                int p = base + 8*eg + i;
                int pp = (p < re) ? p : (re - 1);
                float4 a = *(const float4*)&refr[(size_t)pp * REFW + 4*k4];
                GEMM_STEP(acc[i], a, bf);
            }
        }
        {
            float4 b = *(const float4*)&W_e1[(size_t)128 * H + 4*hg];
            #pragma unroll
            for (int i = 0; i < 8; i++) {
                int p = base + 8*eg + i;
                int pp = (p < re) ? p : (re - 1);
                float a = refr[(size_t)pp * REFW + 16];
                acc[i][0] += a*b.x; acc[i][1] += a*b.y;
                acc[i][2] += a*b.z; acc[i][3] += a*b.w;
            }
        }

        // ---- m = silu(acc) -> LDS ----
        #pragma unroll
        for (int i = 0; i < 8; i++) {
            float4 mv;
            mv.x = silu(acc[i][0]); mv.y = silu(acc[i][1]);
            mv.z = silu(acc[i][2]); mv.w = silu(acc[i][3]);
            *(float4*)&smem[(8*eg+i)*MS + 4*hg] = mv;
        }

        // ---- prefetch next tile into regs (overlaps barrier + MLP2) ----
        float nacc[8][4]; int ndl[8];
        const int nb = base + TE;
        if (nb < re) LOAD_TILE(nb, nacc, ndl);

        __syncthreads();   // m visible to all

        // ---- MLP2: [TE,64] @ W_e2 ----
        float acc2[8][4];
        {
            float4 b0 = *(const float4*)&b_e2[4*hg];
            #pragma unroll
            for (int i = 0; i < 8; i++) {
                acc2[i][0]=b0.x; acc2[i][1]=b0.y; acc2[i][2]=b0.z; acc2[i][3]=b0.w;
            }
        }
        PGEMM64(acc2, W_e2, 0, eg, hg, smem);

        // ---- run-combine within this thread's 8 rows, LDS atomics per run ----
        float rx=0.f, ry=0.f, rz=0.f, rw=0.f;
        int cur = -1;
        #pragma unroll
        for (int i = 0; i < 8; i++) {
            int d = dl[i];
            if (d < 0) continue;
            float vx = silu(acc2[i][0]), vy = silu(acc2[i][1]);
            float vz = silu(acc2[i][2]), vw = silu(acc2[i][3]);
            if (d != cur) {
                if (cur >= 0) {
                    float* hp = &hacc[cur * H + 4*hg];
                    atomicAdd(&hp[0], rx); atomicAdd(&hp[1], ry);
                    atomicAdd(&hp[2], rz); atomicAdd(&hp[3], rw);
                }
                cur = d; rx = vx; ry = vy; rz = vz; rw = vw;
            } else {
                rx += vx; ry += vy; rz += vz; rw += vw;
            }
        }
        if (cur >= 0) {
            float* hp = &hacc[cur * H + 4*hg];
            atomicAdd(&hp[0], rx); atomicAdd(&hp[1], ry);
            atomicAdd(&hp[2], rz); atomicAdd(&hp[3], rw);
        }

        __syncthreads();   // m reads done before next tile overwrites

        #pragma unroll
        for (int i = 0; i < 8; i++) {
            acc[i][0]=nacc[i][0]; acc[i][1]=nacc[i][1];
            acc[i][2]=nacc[i][2]; acc[i][3]=nacc[i][3];
            dl[i]=ndl[i];
        }
    }

    __syncthreads();
    {
        const int dloc = tid >> 4, ch = 4 * (tid & 15);
        int gd = dst0 + dloc;
        if (gd < N) {
            float4 v = *(const float4*)&hacc[dloc * H + ch];
            *(float4*)&h_neigh[(size_t)gd * H + ch] = v;
        }
    }
    #undef LOAD_TILE
}

// ---------------- edge kernel v2 (tier-2 fallback, round-5 proven) ----------------

__global__ __launch_bounds__(256, 4) void edge_kernel2(
    const float* __restrict__ Pa, const float* __restrict__ Pb,
    const float* __restrict__ coord,
    const float* __restrict__ edge_feat,
    const int* __restrict__ eidx, const int* __restrict__ srcs,
    const int* __restrict__ dsts,
    const int* __restrict__ cursor_end, const int* __restrict__ deg,
    const float* __restrict__ W_e1,
    const float* __restrict__ W_e2, const float* __restrict__ b_e2,
    float* __restrict__ h_neigh, int N)
{
    __shared__ float smem[TE * MS];
    __shared__ float hacc[DPB * H];
    __shared__ int ssrc[TE], sdlo[TE], seid[TE];

    const int tid = threadIdx.x;
    const int dst0 = blockIdx.x * DPB;
    const int dlast = min(dst0 + DPB, N) - 1;
    const int rs = cursor_end[dst0] - deg[dst0];
    const int re = cursor_end[dlast];

    for (int i = tid; i < DPB * H; i += 256) hacc[i] = 0.f;

    const int eg = tid >> 4, hg = tid & 15;

    for (int base = rs; base < re; base += TE) {
        const int cnt = min(re - base, TE);
        __syncthreads();

        if (tid < TE) {
            int e = 0, s = 0, dlv = -1;
            float radial = 0.f;
            if (tid < cnt) {
                int p = base + tid;
                e = eidx[p]; s = srcs[p];
                int d2 = dsts[p]; dlv = d2 - dst0;
                float dx = coord[s*3+0] - coord[d2*3+0];
                float dy = coord[s*3+1] - coord[d2*3+1];
                float dz = coord[s*3+2] - coord[d2*3+2];
                radial = dx*dx + dy*dy + dz*dz;
            }
            ssrc[tid] = s; sdlo[tid] = dlv; seid[tid] = e;
            smem[tid * MS + 0] = radial;
        }
        __syncthreads();

        {
            const int k2 = tid & 15, e2 = tid >> 4;
            #pragma unroll
            for (int t = 0; t < 8; t++) {
                int r = e2 + 16*t;
                float v = (sdlo[r] >= 0) ? edge_feat[(size_t)seid[r] * EFD + k2] : 0.f;
                smem[r * MS + 1 + k2] = v;
            }
        }

        float acc[8][4];
        #pragma unroll
        for (int i = 0; i < 8; i++) {
            int r = 8*eg + i;
            int s = ssrc[r];
            int dlv = sdlo[r];
            int drow = (dlv >= 0) ? (dst0 + dlv) : 0;
            float4 pa = *(const float4*)&Pa[(size_t)s * H + 4*hg];
            float4 pb = *(const float4*)&Pb[(size_t)drow * H + 4*hg];
            acc[i][0] = pa.x + pb.x; acc[i][1] = pa.y + pb.y;
            acc[i][2] = pa.z + pb.z; acc[i][3] = pa.w + pb.w;
        }
        __syncthreads();

        for (int k4 = 0; k4 < 4; k4++) {
            float4 bf[4];
            #pragma unroll
            for (int kk = 0; kk < 4; kk++)
                bf[kk] = *(const float4*)&W_e1[(size_t)(128 + 4*k4 + kk) * H + 4*hg];
            #pragma unroll
            for (int i = 0; i < 8; i++) {
                float4 a = *(const float4*)&smem[(8*eg + i) * MS + 4*k4];
                GEMM_STEP(acc[i], a, bf);
            }
        }
        {
            float4 b = *(const float4*)&W_e1[(size_t)144 * H + 4*hg];
            #pragma unroll
            for (int i = 0; i < 8; i++) {
                float a = smem[(8*eg+i)*MS + 16];
                acc[i][0] += a*b.x; acc[i][1] += a*b.y; acc[i][2] += a*b.z; acc[i][3] += a*b.w;
            }
        }
        __syncthreads();

        #pragma unroll
        for (int i = 0; i < 8; i++) {
            float4 mv;
            mv.x = silu(acc[i][0]); mv.y = silu(acc[i][1]);
            mv.z = silu(acc[i][2]); mv.w = silu(acc[i][3]);
            *(float4*)&smem[(8*eg+i)*MS + 4*hg] = mv;
        }
        __syncthreads();

        float acc2[8][4];
        {
            float4 b0 = *(const float4*)&b_e2[4*hg];
            #pragma unroll
            for (int i = 0; i < 8; i++) {
                acc2[i][0]=b0.x; acc2[i][1]=b0.y; acc2[i][2]=b0.z; acc2[i][3]=b0.w;
            }
        }
        PGEMM64(acc2, W_e2, 0, eg, hg, smem);

        float rx=0.f, ry=0.f, rz=0.f, rw=0.f;
        int cur = -1;
        #pragma unroll
        for (int i = 0; i < 8; i++) {
            int r = 8*eg + i;
            int dlv = sdlo[r];
            if (dlv < 0) continue;
            float vx = silu(acc2[i][0]), vy = silu(acc2[i][1]);
            float vz = silu(acc2[i][2]), vw = silu(acc2[i][3]);
            if (dlv != cur) {
                if (cur >= 0) {
                    float* hp = &hacc[cur * H + 4*hg];
                    atomicAdd(&hp[0], rx); atomicAdd(&hp[1], ry);
                    atomicAdd(&hp[2], rz); atomicAdd(&hp[3], rw);
                }
                cur = dlv; rx = vx; ry = vy; rz = vz; rw = vw;
            } else {
                rx += vx; ry += vy; rz += vz; rw += vw;
            }
        }
        if (cur >= 0) {
            float* hp = &hacc[cur * H + 4*hg];
            atomicAdd(&hp[0], rx); atomicAdd(&hp[1], ry);
            atomicAdd(&hp[2], rz); atomicAdd(&hp[3], rw);
        }
    }

    __syncthreads();
    {
        const int dloc = tid >> 4, ch = 4 * (tid & 15);
        int gd = dst0 + dloc;
        if (gd < N) {
            float4 v = *(const float4*)&hacc[dloc * H + ch];
            *(float4*)&h_neigh[(size_t)gd * H + ch] = v;
        }
    }
}

// ---------------- node kernel ----------------

__global__ __launch_bounds__(256, 4) void node_kernel(
    const float* __restrict__ node_feat,
    const float* __restrict__ h_neigh,
    const float* __restrict__ W_n1, const float* __restrict__ b_n1,
    const float* __restrict__ W_n2, const float* __restrict__ b_n2,
    float* __restrict__ out, int N)
{
    __shared__ float smem[TN * MS];

    const int tid = threadIdx.x;
    const int nbase = blockIdx.x * TN;

    const int ng = tid >> 4, hg = tid & 15, k = tid & 63, no = tid >> 6;

    float acc[8][4];
    {
        float4 b0 = *(const float4*)&b_n1[4*hg];
        #pragma unroll
        for (int i = 0; i < 8; i++) {
            acc[i][0]=b0.x; acc[i][1]=b0.y; acc[i][2]=b0.z; acc[i][3]=b0.w;
        }
    }

    float rA[32];
    #pragma unroll
    for (int t = 0; t < 32; t++) {
        int gn = nbase + no + 4*t;
        int cg = (gn < N) ? gn : (N - 1);
        rA[t] = node_feat[(size_t)cg * D + k];
    }
    #pragma unroll
    for (int t = 0; t < 32; t++)
        smem[(no + 4*t) * MS + k] = rA[t];
    __syncthreads();

    float rB[32];
    #pragma unroll
    for (int t = 0; t < 32; t++) {
        int gn = nbase + no + 4*t;
        int cg = (gn < N) ? gn : (N - 1);
        rB[t] = h_neigh[(size_t)cg * H + k];
    }
    PGEMM64(acc, W_n1, 0, ng, hg, smem);
    __syncthreads();

    #pragma unroll
    for (int t = 0; t < 32; t++)
        smem[(no + 4*t) * MS + k] = rB[t];
    __syncthreads();

    PGEMM64(acc, W_n1, 64, ng, hg, smem);
    __syncthreads();

    #pragma unroll
    for (int i = 0; i < 8; i++) {
        float4 mv;
        mv.x = silu(acc[i][0]); mv.y = silu(acc[i][1]);
        mv.z = silu(acc[i][2]); mv.w = silu(acc[i][3]);
        *(float4*)&smem[(8*ng+i)*MS + 4*hg] = mv;
    }
    __syncthreads();

    float acc2[8][4];
    {
        float4 b0 = *(const float4*)&b_n2[4*hg];
        #pragma unroll
        for (int i = 0; i < 8; i++) {
            acc2[i][0]=b0.x; acc2[i][1]=b0.y; acc2[i][2]=b0.z; acc2[i][3]=b0.w;
        }
    }
    PGEMM64(acc2, W_n2, 0, ng, hg, smem);

    #pragma unroll
    for (int i = 0; i < 8; i++) {
        int gn = nbase + 8*ng + i;
        if (gn < N) {
            float4 ov;
            ov.x = acc2[i][0]; ov.y = acc2[i][1]; ov.z = acc2[i][2]; ov.w = acc2[i][3];
            *(float4*)&out[(size_t)gn * D + 4*hg] = ov;
        }
    }
}

extern "C" void kernel_launch(void* const* d_in, const int* in_sizes, int n_in,
                              void* d_out, int out_size, void* d_ws, size_t ws_size,
                              hipStream_t stream)
{
    const float* node_feat = (const float*)d_in[0];
    const float* coord     = (const float*)d_in[1];
    const float* edge_feat = (const float*)d_in[2];
    const int*   src       = (const int*)d_in[3];
    const int*   dst       = (const int*)d_in[4];
    const float* W_e1 = (const float*)d_in[5];
    const float* b_e1 = (const float*)d_in[6];
    const float* W_e2 = (const float*)d_in[7];
    const float* b_e2 = (const float*)d_in[8];
    const float* W_n1 = (const float*)d_in[9];
    const float* b_n1 = (const float*)d_in[10];
    const float* W_n2 = (const float*)d_in[11];
    const float* b_n2 = (const float*)d_in[12];

    const int N = in_sizes[0] / D;
    const int E = in_sizes[3];
    const int NP = (N + 255) / 256;           // scan partial blocks

    const size_t hn_b  = (size_t)N * H * sizeof(float);
    const size_t n_i   = (size_t)N * sizeof(int);
    const size_t e_i   = (size_t)E * sizeof(int);
    const size_t pt_b  = 1024 * sizeof(int);
    const size_t p_b   = (size_t)N * H * sizeof(float);
    const size_t rf_b  = (size_t)E * REFW * sizeof(float);

    // tier3: h_neigh | deg | cursor | part | srcs | dsts | refr | Pa | Pb
    const size_t need3 = hn_b + 2*n_i + pt_b + 2*e_i + rf_b + 2*p_b;
    // tier2: h_neigh | deg | cursor | part | eidx | srcs | dsts | Pa | Pb
    const size_t need2 = hn_b + 2*n_i + pt_b + 3*e_i + 2*p_b;

    float* h_neigh = (float*)d_ws;
    const int dblocks = (N + DPB - 1) / DPB;

    if (ws_size >= need3) {
        char* p = (char*)d_ws + hn_b;
        int* deg    = (int*)p;   p += n_i;
        int* cursor = (int*)p;   p += n_i;
        int* part   = (int*)p;   p += pt_b;
        int* srcs   = (int*)p;   p += e_i;
        int* dsts   = (int*)p;   p += e_i;
        float* refr = (float*)p; p += rf_b;
        float* Pa   = (float*)p; p += p_b;
        float* Pb   = (float*)p;

        hipMemsetAsync(deg, 0, n_i, stream);
        hist_kernel<<<(E + 255) / 256, 256, 0, stream>>>(dst, deg, E);
        scanA_kernel<<<NP, 256, 0, stream>>>(deg, part, N);
        scanB_kernel<<<1, 256, 0, stream>>>(part, NP);
        scanC_kernel<<<NP, 256, 0, stream>>>(deg, part, cursor, N);
        build3_kernel<<<(E + 255) / 256, 256, 0, stream>>>(dst, src, coord, edge_feat,
                                                           cursor, srcs, dsts, refr, E);
        pre_kernel<<<(N + TN - 1) / TN, 256, 0, stream>>>(node_feat, W_e1, b_e1,
                                                          Pa, Pb, N);
        edge_kernel3<<<dblocks, 256, 0, stream>>>(Pa, Pb, srcs, dsts, refr,
                                                  cursor, deg,
                                                  W_e1, W_e2, b_e2, h_neigh, N);
    } else {
        // tier2 (round-5 proven path)
        char* p = (char*)d_ws + hn_b;
        int* deg    = (int*)p;   p += n_i;
        int* cursor = (int*)p;   p += n_i;
        int* part   = (int*)p;   p += pt_b;
        int* eidx   = (int*)p;   p += e_i;
        int* srcs   = (int*)p;   p += e_i;
        int* dsts   = (int*)p;   p += e_i;
        float* Pa   = (float*)p; p += p_b;
        float* Pb   = (float*)p;

        hipMemsetAsync(deg, 0, n_i, stream);
        hist_kernel<<<(E + 255) / 256, 256, 0, stream>>>(dst, deg, E);
        scanA_kernel<<<NP, 256, 0, stream>>>(deg, part, N);
        scanB_kernel<<<1, 256, 0, stream>>>(part, NP);
        scanC_kernel<<<NP, 256, 0, stream>>>(deg, part, cursor, N);
        build2_kernel<<<(E + 255) / 256, 256, 0, stream>>>(dst, src, cursor,
                                                           eidx, srcs, dsts, E);
        pre_kernel<<<(N + TN - 1) / TN, 256, 0, stream>>>(node_feat, W_e1, b_e1,
                                                          Pa, Pb, N);
        edge_kernel2<<<dblocks, 256, 0, stream>>>(Pa, Pb, coord, edge_feat,
                                                  eidx, srcs, dsts, cursor, deg,
                                                  W_e1, W_e2, b_e2, h_neigh, N);
    }

    const int nblocks = (N + TN - 1) / TN;
    node_kernel<<<nblocks, 256, 0, stream>>>(node_feat, h_neigh,
                                             W_n1, b_n1, W_n2, b_n2,
                                             (float*)d_out, N);
}

// Round 8
// 525.811 us; speedup vs baseline: 2.0355x; 1.1608x over previous
//
#include <hip/hip_runtime.h>

#define D 64
#define H 64
#define EFD 16
#define MS 68    // LDS tile row stride (floats) for legacy kernels
#define TE 128   // edges per tile
#define TN 128   // nodes per block
#define DPB 16   // dsts per block (tier-2 edge_kernel2)
#define DPB4 32  // dsts per block (edge_kernel4)
#define REFW 20  // packed [ef(16)|radial|pad3] row stride (floats), 80B

typedef __attribute__((ext_vector_type(8))) short bf16x8;
typedef __attribute__((ext_vector_type(4))) float f32x4;

__device__ __forceinline__ float silu(float x) {
    return x / (1.0f + __expf(-x));
}

__device__ __forceinline__ short f2bf(float x) {   // RNE fp32->bf16
    union { float f; unsigned u; } c; c.f = x;
    unsigned r = c.u + 0x7fffu + ((c.u >> 16) & 1u);
    return (short)(r >> 16);
}

#define GEMM_STEP(acc_, a_, bf_) do { \
    const float* bp_ = (const float*)(bf_); \
    acc_[0] += (a_).x*bp_[0] + (a_).y*bp_[4] + (a_).z*bp_[8]  + (a_).w*bp_[12]; \
    acc_[1] += (a_).x*bp_[1] + (a_).y*bp_[5] + (a_).z*bp_[9]  + (a_).w*bp_[13]; \
    acc_[2] += (a_).x*bp_[2] + (a_).y*bp_[6] + (a_).z*bp_[10] + (a_).w*bp_[14]; \
    acc_[3] += (a_).x*bp_[3] + (a_).y*bp_[7] + (a_).z*bp_[11] + (a_).w*bp_[15]; \
} while (0)

#define PGEMM64(acc_, Wp_, wrow0_, eg_, hg_, smem_) do { \
    for (int k4 = 0; k4 < 16; k4++) { \
        float4 bf_[4]; \
        _Pragma("unroll") \
        for (int kk = 0; kk < 4; kk++) \
            bf_[kk] = *(const float4*)&(Wp_)[(size_t)((wrow0_) + 4*k4 + kk) * H + 4*(hg_)]; \
        _Pragma("unroll") \
        for (int i = 0; i < 8; i++) { \
            float4 a_ = *(const float4*)&(smem_)[(8*(eg_) + i) * MS + 4*k4]; \
            GEMM_STEP(acc_[i], a_, bf_); \
        } \
    } \
} while (0)

// ---------------- histogram ----------------

__global__ __launch_bounds__(256) void hist_kernel(
    const int* __restrict__ dst, int* __restrict__ deg, int E)
{
    int e = blockIdx.x * 256 + threadIdx.x;
    if (e < E) atomicAdd(&deg[dst[e]], 1);
}

// ---------------- 3-phase multi-block exclusive scan ----------------

__global__ __launch_bounds__(256) void scanA_kernel(
    const int* __restrict__ deg, int* __restrict__ part, int N)
{
    __shared__ int tmp[256];
    const int tid = threadIdx.x;
    int idx = blockIdx.x * 256 + tid;
    tmp[tid] = (idx < N) ? deg[idx] : 0;
    __syncthreads();
    for (int off = 128; off > 0; off >>= 1) {
        if (tid < off) tmp[tid] += tmp[tid + off];
        __syncthreads();
    }
    if (tid == 0) part[blockIdx.x] = tmp[0];
}

__global__ __launch_bounds__(256, 1) void scanB_kernel(
    int* __restrict__ part, int nparts)
{
    __shared__ int tmp[256];
    __shared__ int carry_s;
    const int tid = threadIdx.x;
    if (tid == 0) carry_s = 0;
    __syncthreads();
    for (int base = 0; base < nparts; base += 256) {
        int idx = base + tid;
        int v = (idx < nparts) ? part[idx] : 0;
        tmp[tid] = v;
        __syncthreads();
        #pragma unroll
        for (int off = 1; off < 256; off <<= 1) {
            int t = (tid >= off) ? tmp[tid - off] : 0;
            __syncthreads();
            tmp[tid] += t;
            __syncthreads();
        }
        int incl = tmp[tid];
        int tot = tmp[255];
        if (idx < nparts) part[idx] = carry_s + incl - v;  // exclusive
        __syncthreads();
        if (tid == 0) carry_s += tot;
        __syncthreads();
    }
}

__global__ __launch_bounds__(256) void scanC_kernel(
    const int* __restrict__ deg, const int* __restrict__ part,
    int* __restrict__ cursor, int N)
{
    __shared__ int tmp[256];
    const int tid = threadIdx.x;
    int idx = blockIdx.x * 256 + tid;
    int v = (idx < N) ? deg[idx] : 0;
    tmp[tid] = v;
    __syncthreads();
    #pragma unroll
    for (int off = 1; off < 256; off <<= 1) {
        int t = (tid >= off) ? tmp[tid - off] : 0;
        __syncthreads();
        tmp[tid] += t;
        __syncthreads();
    }
    if (idx < N) cursor[idx] = part[blockIdx.x] + tmp[tid] - v;
}

// ---------------- build: sort all per-edge data by dst ----------------

__global__ __launch_bounds__(256) void build3_kernel(
    const int* __restrict__ dst, const int* __restrict__ src,
    const float* __restrict__ coord, const float* __restrict__ edge_feat,
    int* __restrict__ cursor,
    int* __restrict__ srcs, int* __restrict__ dsts, float* __restrict__ refr,
    int E)
{
    int e = blockIdx.x * 256 + threadIdx.x;
    if (e >= E) return;
    int d2 = dst[e];
    int s = src[e];
    int pos = atomicAdd(&cursor[d2], 1);
    srcs[pos] = s;
    dsts[pos] = d2;
    float dx = coord[s*3+0] - coord[d2*3+0];
    float dy = coord[s*3+1] - coord[d2*3+1];
    float dz = coord[s*3+2] - coord[d2*3+2];
    float* rr = &refr[(size_t)pos * REFW];
    const float4* ef = (const float4*)&edge_feat[(size_t)e * EFD];
    *(float4*)&rr[0]  = ef[0];
    *(float4*)&rr[4]  = ef[1];
    *(float4*)&rr[8]  = ef[2];
    *(float4*)&rr[12] = ef[3];
    rr[16] = dx*dx + dy*dy + dz*dz;
}

__global__ __launch_bounds__(256) void build2_kernel(
    const int* __restrict__ dst, const int* __restrict__ src,
    int* __restrict__ cursor,
    int* __restrict__ eidx, int* __restrict__ srcs, int* __restrict__ dsts,
    int E)
{
    int e = blockIdx.x * 256 + threadIdx.x;
    if (e < E) {
        int d2 = dst[e];
        int pos = atomicAdd(&cursor[d2], 1);
        eidx[pos] = e;
        srcs[pos] = src[e];
        dsts[pos] = d2;
    }
}

// ---------------- Pa/Pb precompute ----------------

__global__ __launch_bounds__(256, 4) void pre_kernel(
    const float* __restrict__ node_feat,
    const float* __restrict__ W_e1, const float* __restrict__ b_e1,
    float* __restrict__ Pa, float* __restrict__ Pb, int N)
{
    __shared__ float smem[TN * MS];
    const int tid = threadIdx.x;
    const int nbase = blockIdx.x * TN;
    const int ng = tid >> 4, hg = tid & 15, k = tid & 63, no = tid >> 6;

    #pragma unroll
    for (int t = 0; t < 32; t++) {
        int gn = nbase + no + 4*t;
        int cg = (gn < N) ? gn : (N - 1);
        smem[(no + 4*t) * MS + k] = node_feat[(size_t)cg * D + k];
    }
    __syncthreads();

    float accA[8][4], accB[8][4];
    {
        float4 b0 = *(const float4*)&b_e1[4*hg];
        #pragma unroll
        for (int i = 0; i < 8; i++) {
            accA[i][0]=b0.x; accA[i][1]=b0.y; accA[i][2]=b0.z; accA[i][3]=b0.w;
            accB[i][0]=0.f;  accB[i][1]=0.f;  accB[i][2]=0.f;  accB[i][3]=0.f;
        }
    }
    PGEMM64(accA, W_e1, 0,  ng, hg, smem);
    PGEMM64(accB, W_e1, 64, ng, hg, smem);

    #pragma unroll
    for (int i = 0; i < 8; i++) {
        int gn = nbase + 8*ng + i;
        if (gn < N) {
            float4 a; a.x=accA[i][0]; a.y=accA[i][1]; a.z=accA[i][2]; a.w=accA[i][3];
            float4 b; b.x=accB[i][0]; b.y=accB[i][1]; b.z=accB[i][2]; b.w=accB[i][3];
            *(float4*)&Pa[(size_t)gn * H + 4*hg] = a;
            *(float4*)&Pb[(size_t)gn * H + 4*hg] = b;
        }
    }
}

// ---------------- edge kernel v4: barrier-free tile loop + MFMA MLP2 ----------------
// Wave-private m slices: wave w owns rows 32w..32w+31 of the bf16 m-tile.
// LDS m-tile XOR-swizzled: short-index ^= (row&7)<<3  (16B-slot spread, T2).

__global__ __launch_bounds__(256, 3) void edge_kernel4(
    const float* __restrict__ Pa, const float* __restrict__ Pb,
    const int* __restrict__ srcs, const int* __restrict__ dsts,
    const float* __restrict__ refr,
    const int* __restrict__ cursor_end, const int* __restrict__ deg,
    const float* __restrict__ W_e1,
    const float* __restrict__ W_e2, const float* __restrict__ b_e2,
    float* __restrict__ h_neigh, int N)
{
    __shared__ alignas(16) short mt[TE * H];   // bf16 m tile (16 KB)
    __shared__ float hacc[DPB4 * H];           // per-dst accumulator (8 KB)

    const int tid = threadIdx.x;
    const int lane = tid & 63;
    const int wv = tid >> 6;       // wave 0..3
    const int lg = lane >> 4;      // k-group 0..3
    const int lc = lane & 15;      // row/col-in-frag
    const int eg = tid >> 4;       // 0..15 (phase-1 row group)
    const int hg = tid & 15;       // 0..15 (phase-1 col group)

    const int dst0 = blockIdx.x * DPB4;
    const int dlast = min(dst0 + DPB4, N) - 1;
    const int rs = cursor_end[dst0] - deg[dst0];
    const int re = cursor_end[dlast];

    for (int i = tid; i < DPB4 * H; i += 256) hacc[i] = 0.f;

    // ---- W_e2 as bf16 B-fragments, once per block (L1-hot strided loads) ----
    // B[k][col], k = lg*8 + t + 32*ks, col = 16*nf + lc
    bf16x8 bfr[2][4];
    #pragma unroll
    for (int ks = 0; ks < 2; ks++)
        #pragma unroll
        for (int nf = 0; nf < 4; nf++) {
            bf16x8 v;
            #pragma unroll
            for (int t = 0; t < 8; t++)
                v[t] = f2bf(W_e2[(size_t)(lg*8 + t + 32*ks) * H + 16*nf + lc]);
            bfr[ks][nf] = v;
        }
    float bias[4];
    #pragma unroll
    for (int nf = 0; nf < 4; nf++) bias[nf] = b_e2[16*nf + lc];

    __syncthreads();   // hacc init visible before any atomics

    for (int base = rs; base < re; base += TE) {
        // ---- phase 1 (fp32): rows 8eg..8eg+7 -> acc = Pa[src]+Pb[dst] + [ef|radial]@W1c ----
        float a1[8][4];
        #pragma unroll
        for (int i = 0; i < 8; i++) {
            int p = base + 8*eg + i;
            int pp = (p < re) ? p : (re - 1);
            int s = srcs[pp], d2 = dsts[pp];
            float4 pa = *(const float4*)&Pa[(size_t)s * H + 4*hg];
            float4 pb = *(const float4*)&Pb[(size_t)d2 * H + 4*hg];
            a1[i][0] = pa.x + pb.x; a1[i][1] = pa.y + pb.y;
            a1[i][2] = pa.z + pb.z; a1[i][3] = pa.w + pb.w;
        }
        for (int k4 = 0; k4 < 4; k4++) {
            float4 bf[4];
            #pragma unroll
            for (int kk = 0; kk < 4; kk++)
                bf[kk] = *(const float4*)&W_e1[(size_t)(129 + 4*k4 + kk) * H + 4*hg];
            #pragma unroll
            for (int i = 0; i < 8; i++) {
                int p = base + 8*eg + i;
                int pp = (p < re) ? p : (re - 1);
                float4 a = *(const float4*)&refr[(size_t)pp * REFW + 4*k4];
                GEMM_STEP(a1[i], a, bf);
            }
        }
        {
            float4 b = *(const float4*)&W_e1[(size_t)128 * H + 4*hg];
            #pragma unroll
            for (int i = 0; i < 8; i++) {
                int p = base + 8*eg + i;
                int pp = (p < re) ? p : (re - 1);
                float a = refr[(size_t)pp * REFW + 16];
                a1[i][0] += a*b.x; a1[i][1] += a*b.y;
                a1[i][2] += a*b.z; a1[i][3] += a*b.w;
            }
        }

        // ---- m = silu(acc) -> bf16 -> swizzled LDS (wave-private rows) ----
        #pragma unroll
        for (int i = 0; i < 8; i++) {
            short4 mv;
            mv.x = f2bf(silu(a1[i][0])); mv.y = f2bf(silu(a1[i][1]));
            mv.z = f2bf(silu(a1[i][2])); mv.w = f2bf(silu(a1[i][3]));
            int row = 8*eg + i;                      // row&7 == i
            int sidx = (row * H + 4*hg) ^ (i << 3);
            *(short4*)&mt[sidx] = mv;
        }
        asm volatile("s_waitcnt lgkmcnt(0)" ::: "memory");  // DS in-order/wave; belt+suspenders

        // ---- MLP2 via MFMA: wave w computes rows 32w..32w+31, all 64 cols ----
        // A[row][k]: row = 32wv+16mf+lc, k = lg*8 + t + 32ks
        bf16x8 afr[2][2];
        #pragma unroll
        for (int mf = 0; mf < 2; mf++)
            #pragma unroll
            for (int ks = 0; ks < 2; ks++) {
                int row = 32*wv + 16*mf + lc;
                int sidx = (row * H + lg*8 + 32*ks) ^ ((lc & 7) << 3);
                afr[mf][ks] = *(const bf16x8*)&mt[sidx];
            }
        f32x4 c2[2][4];
        #pragma unroll
        for (int mf = 0; mf < 2; mf++)
            #pragma unroll
            for (int nf = 0; nf < 4; nf++) {
                f32x4 cinit = {bias[nf], bias[nf], bias[nf], bias[nf]};
                c2[mf][nf] = cinit;
            }
        #pragma unroll
        for (int ks = 0; ks < 2; ks++)
            #pragma unroll
            for (int mf = 0; mf < 2; mf++)
                #pragma unroll
                for (int nf = 0; nf < 4; nf++)
                    c2[mf][nf] = __builtin_amdgcn_mfma_f32_16x16x32_bf16(
                        afr[mf][ks], bfr[ks][nf], c2[mf][nf], 0, 0, 0);

        // ---- epilogue: D[r][c] r=(lg*4+reg), c=lc+16nf; silu + run-combine + LDS atomics ----
        #pragma unroll
        for (int mf = 0; mf < 2; mf++) {
            int rb = 32*wv + 16*mf + 4*lg;
            int cur = -1;
            float s0 = 0.f, s1 = 0.f, s2 = 0.f, s3 = 0.f;
            #pragma unroll
            for (int reg = 0; reg < 4; reg++) {
                int p = base + rb + reg;
                if (p < re) {
                    int dl = dsts[p] - dst0;
                    float v0 = silu(c2[mf][0][reg]);
                    float v1 = silu(c2[mf][1][reg]);
                    float v2 = silu(c2[mf][2][reg]);
                    float v3 = silu(c2[mf][3][reg]);
                    if (dl != cur) {
                        if (cur >= 0) {
                            atomicAdd(&hacc[cur*H + lc],      s0);
                            atomicAdd(&hacc[cur*H + 16 + lc], s1);
                            atomicAdd(&hacc[cur*H + 32 + lc], s2);
                            atomicAdd(&hacc[cur*H + 48 + lc], s3);
                        }
                        cur = dl; s0 = v0; s1 = v1; s2 = v2; s3 = v3;
                    } else { s0 += v0; s1 += v1; s2 += v2; s3 += v3; }
                }
            }
            if (cur >= 0) {
                atomicAdd(&hacc[cur*H + lc],      s0);
                atomicAdd(&hacc[cur*H + 16 + lc], s1);
                atomicAdd(&hacc[cur*H + 32 + lc], s2);
                atomicAdd(&hacc[cur*H + 48 + lc], s3);
            }
        }
    }

    __syncthreads();
    #pragma unroll
    for (int t = 0; t < 2; t++) {
        int idx = tid + t*256;          // 512 float4 groups total
        int dloc = idx >> 4;
        int ch = (idx & 15) * 4;
        int gd = dst0 + dloc;
        if (gd < N)
            *(float4*)&h_neigh[(size_t)gd * H + ch] =
                *(const float4*)&hacc[dloc * H + ch];
    }
}

// ---------------- edge kernel v2 (tier-2 fallback) ----------------

__global__ __launch_bounds__(256, 4) void edge_kernel2(
    const float* __restrict__ Pa, const float* __restrict__ Pb,
    const float* __restrict__ coord,
    const float* __restrict__ edge_feat,
    const int* __restrict__ eidx, const int* __restrict__ srcs,
    const int* __restrict__ dsts,
    const int* __restrict__ cursor_end, const int* __restrict__ deg,
    const float* __restrict__ W_e1,
    const float* __restrict__ W_e2, const float* __restrict__ b_e2,
    float* __restrict__ h_neigh, int N)
{
    __shared__ float smem[TE * MS];
    __shared__ float hacc[DPB * H];
    __shared__ int ssrc[TE], sdlo[TE], seid[TE];

    const int tid = threadIdx.x;
    const int dst0 = blockIdx.x * DPB;
    const int dlast = min(dst0 + DPB, N) - 1;
    const int rs = cursor_end[dst0] - deg[dst0];
    const int re = cursor_end[dlast];

    for (int i = tid; i < DPB * H; i += 256) hacc[i] = 0.f;

    const int eg = tid >> 4, hg = tid & 15;

    for (int base = rs; base < re; base += TE) {
        const int cnt = min(re - base, TE);
        __syncthreads();

        if (tid < TE) {
            int e = 0, s = 0, dlv = -1;
            float radial = 0.f;
            if (tid < cnt) {
                int p = base + tid;
                e = eidx[p]; s = srcs[p];
                int d2 = dsts[p]; dlv = d2 - dst0;
                float dx = coord[s*3+0] - coord[d2*3+0];
                float dy = coord[s*3+1] - coord[d2*3+1];
                float dz = coord[s*3+2] - coord[d2*3+2];
                radial = dx*dx + dy*dy + dz*dz;
            }
            ssrc[tid] = s; sdlo[tid] = dlv; seid[tid] = e;
            smem[tid * MS + 0] = radial;
        }
        __syncthreads();

        {
            const int k2 = tid & 15, e2 = tid >> 4;
            #pragma unroll
            for (int t = 0; t < 8; t++) {
                int r = e2 + 16*t;
                float v = (sdlo[r] >= 0) ? edge_feat[(size_t)seid[r] * EFD + k2] : 0.f;
                smem[r * MS + 1 + k2] = v;
            }
        }

        float acc[8][4];
        #pragma unroll
        for (int i = 0; i < 8; i++) {
            int r = 8*eg + i;
            int s = ssrc[r];
            int dlv = sdlo[r];
            int drow = (dlv >= 0) ? (dst0 + dlv) : 0;
            float4 pa = *(const float4*)&Pa[(size_t)s * H + 4*hg];
            float4 pb = *(const float4*)&Pb[(size_t)drow * H + 4*hg];
            acc[i][0] = pa.x + pb.x; acc[i][1] = pa.y + pb.y;
            acc[i][2] = pa.z + pb.z; acc[i][3] = pa.w + pb.w;
        }
        __syncthreads();

        for (int k4 = 0; k4 < 4; k4++) {
            float4 bf[4];
            #pragma unroll
            for (int kk = 0; kk < 4; kk++)
                bf[kk] = *(const float4*)&W_e1[(size_t)(128 + 4*k4 + kk) * H + 4*hg];
            #pragma unroll
            for (int i = 0; i < 8; i++) {
                float4 a = *(const float4*)&smem[(8*eg + i) * MS + 4*k4];
                GEMM_STEP(acc[i], a, bf);
            }
        }
        {
            float4 b = *(const float4*)&W_e1[(size_t)144 * H + 4*hg];
            #pragma unroll
            for (int i = 0; i < 8; i++) {
                float a = smem[(8*eg+i)*MS + 16];
                acc[i][0] += a*b.x; acc[i][1] += a*b.y; acc[i][2] += a*b.z; acc[i][3] += a*b.w;
            }
        }
        __syncthreads();

        #pragma unroll
        for (int i = 0; i < 8; i++) {
            float4 mv;
            mv.x = silu(acc[i][0]); mv.y = silu(acc[i][1]);
            mv.z = silu(acc[i][2]); mv.w = silu(acc[i][3]);
            *(float4*)&smem[(8*eg+i)*MS + 4*hg] = mv;
        }
        __syncthreads();

        float acc2[8][4];
        {
            float4 b0 = *(const float4*)&b_e2[4*hg];
            #pragma unroll
            for (int i = 0; i < 8; i++) {
                acc2[i][0]=b0.x; acc2[i][1]=b0.y; acc2[i][2]=b0.z; acc2[i][3]=b0.w;
            }
        }
        PGEMM64(acc2, W_e2, 0, eg, hg, smem);

        float rx=0.f, ry=0.f, rz=0.f, rw=0.f;
        int cur = -1;
        #pragma unroll
        for (int i = 0; i < 8; i++) {
            int r = 8*eg + i;
            int dlv = sdlo[r];
            if (dlv < 0) continue;
            float vx = silu(acc2[i][0]), vy = silu(acc2[i][1]);
            float vz = silu(acc2[i][2]), vw = silu(acc2[i][3]);
            if (dlv != cur) {
                if (cur >= 0) {
                    float* hp = &hacc[cur * H + 4*hg];
                    atomicAdd(&hp[0], rx); atomicAdd(&hp[1], ry);
                    atomicAdd(&hp[2], rz); atomicAdd(&hp[3], rw);
                }
                cur = dlv; rx = vx; ry = vy; rz = vz; rw = vw;
            } else {
                rx += vx; ry += vy; rz += vz; rw += vw;
            }
        }
        if (cur >= 0) {
            float* hp = &hacc[cur * H + 4*hg];
            atomicAdd(&hp[0], rx); atomicAdd(&hp[1], ry);
            atomicAdd(&hp[2], rz); atomicAdd(&hp[3], rw);
        }
    }

    __syncthreads();
    {
        const int dloc = tid >> 4, ch = 4 * (tid & 15);
        int gd = dst0 + dloc;
        if (gd < N) {
            float4 v = *(const float4*)&hacc[dloc * H + ch];
            *(float4*)&h_neigh[(size_t)gd * H + ch] = v;
        }
    }
}

// ---------------- node kernel ----------------

__global__ __launch_bounds__(256, 4) void node_kernel(
    const float* __restrict__ node_feat,
    const float* __restrict__ h_neigh,
    const float* __restrict__ W_n1, const float* __restrict__ b_n1,
    const float* __restrict__ W_n2, const float* __restrict__ b_n2,
    float* __restrict__ out, int N)
{
    __shared__ float smem[TN * MS];

    const int tid = threadIdx.x;
    const int nbase = blockIdx.x * TN;

    const int ng = tid >> 4, hg = tid & 15, k = tid & 63, no = tid >> 6;

    float acc[8][4];
    {
        float4 b0 = *(const float4*)&b_n1[4*hg];
        #pragma unroll
        for (int i = 0; i < 8; i++) {
            acc[i][0]=b0.x; acc[i][1]=b0.y; acc[i][2]=b0.z; acc[i][3]=b0.w;
        }
    }

    float rA[32];
    #pragma unroll
    for (int t = 0; t < 32; t++) {
        int gn = nbase + no + 4*t;
        int cg = (gn < N) ? gn : (N - 1);
        rA[t] = node_feat[(size_t)cg * D + k];
    }
    #pragma unroll
    for (int t = 0; t < 32; t++)
        smem[(no + 4*t) * MS + k] = rA[t];
    __syncthreads();

    float rB[32];
    #pragma unroll
    for (int t = 0; t < 32; t++) {
        int gn = nbase + no + 4*t;
        int cg = (gn < N) ? gn : (N - 1);
        rB[t] = h_neigh[(size_t)cg * H + k];
    }
    PGEMM64(acc, W_n1, 0, ng, hg, smem);
    __syncthreads();

    #pragma unroll
    for (int t = 0; t < 32; t++)
        smem[(no + 4*t) * MS + k] = rB[t];
    __syncthreads();

    PGEMM64(acc, W_n1, 64, ng, hg, smem);
    __syncthreads();

    #pragma unroll
    for (int i = 0; i < 8; i++) {
        float4 mv;
        mv.x = silu(acc[i][0]); mv.y = silu(acc[i][1]);
        mv.z = silu(acc[i][2]); mv.w = silu(acc[i][3]);
        *(float4*)&smem[(8*ng+i)*MS + 4*hg] = mv;
    }
    __syncthreads();

    float acc2[8][4];
    {
        float4 b0 = *(const float4*)&b_n2[4*hg];
        #pragma unroll
        for (int i = 0; i < 8; i++) {
            acc2[i][0]=b0.x; acc2[i][1]=b0.y; acc2[i][2]=b0.z; acc2[i][3]=b0.w;
        }
    }
    PGEMM64(acc2, W_n2, 0, ng, hg, smem);

    #pragma unroll
    for (int i = 0; i < 8; i++) {
        int gn = nbase + 8*ng + i;
        if (gn < N) {
            float4 ov;
            ov.x = acc2[i][0]; ov.y = acc2[i][1]; ov.z = acc2[i][2]; ov.w = acc2[i][3];
            *(float4*)&out[(size_t)gn * D + 4*hg] = ov;
        }
    }
}

extern "C" void kernel_launch(void* const* d_in, const int* in_sizes, int n_in,
                              void* d_out, int out_size, void* d_ws, size_t ws_size,
                              hipStream_t stream)
{
    const float* node_feat = (const float*)d_in[0];
    const float* coord     = (const float*)d_in[1];
    const float* edge_feat = (const float*)d_in[2];
    const int*   src       = (const int*)d_in[3];
    const int*   dst       = (const int*)d_in[4];
    const float* W_e1 = (const float*)d_in[5];
    const float* b_e1 = (const float*)d_in[6];
    const float* W_e2 = (const float*)d_in[7];
    const float* b_e2 = (const float*)d_in[8];
    const float* W_n1 = (const float*)d_in[9];
    const float* b_n1 = (const float*)d_in[10];
    const float* W_n2 = (const float*)d_in[11];
    const float* b_n2 = (const float*)d_in[12];

    const int N = in_sizes[0] / D;
    const int E = in_sizes[3];
    const int NP = (N + 255) / 256;

    const size_t hn_b  = (size_t)N * H * sizeof(float);
    const size_t n_i   = (size_t)N * sizeof(int);
    const size_t e_i   = (size_t)E * sizeof(int);
    const size_t pt_b  = 1024 * sizeof(int);
    const size_t p_b   = (size_t)N * H * sizeof(float);
    const size_t rf_b  = (size_t)E * REFW * sizeof(float);

    // tier3: h_neigh | deg | cursor | part | srcs | dsts | refr | Pa | Pb
    const size_t need3 = hn_b + 2*n_i + pt_b + 2*e_i + rf_b + 2*p_b;

    float* h_neigh = (float*)d_ws;

    if (ws_size >= need3) {
        char* p = (char*)d_ws + hn_b;
        int* deg    = (int*)p;   p += n_i;
        int* cursor = (int*)p;   p += n_i;
        int* part   = (int*)p;   p += pt_b;
        int* srcs   = (int*)p;   p += e_i;
        int* dsts   = (int*)p;   p += e_i;
        float* refr = (float*)p; p += rf_b;
        float* Pa   = (float*)p; p += p_b;
        float* Pb   = (float*)p;

        hipMemsetAsync(deg, 0, n_i, stream);
        hist_kernel<<<(E + 255) / 256, 256, 0, stream>>>(dst, deg, E);
        scanA_kernel<<<NP, 256, 0, stream>>>(deg, part, N);
        scanB_kernel<<<1, 256, 0, stream>>>(part, NP);
        scanC_kernel<<<NP, 256, 0, stream>>>(deg, part, cursor, N);
        build3_kernel<<<(E + 255) / 256, 256, 0, stream>>>(dst, src, coord, edge_feat,
                                                           cursor, srcs, dsts, refr, E);
        pre_kernel<<<(N + TN - 1) / TN, 256, 0, stream>>>(node_feat, W_e1, b_e1,
                                                          Pa, Pb, N);
        const int dblocks = (N + DPB4 - 1) / DPB4;
        edge_kernel4<<<dblocks, 256, 0, stream>>>(Pa, Pb, srcs, dsts, refr,
                                                  cursor, deg,
                                                  W_e1, W_e2, b_e2, h_neigh, N);
    } else {
        // tier2 (round-5 proven path)
        char* p = (char*)d_ws + hn_b;
        int* deg    = (int*)p;   p += n_i;
        int* cursor = (int*)p;   p += n_i;
        int* part   = (int*)p;   p += pt_b;
        int* eidx   = (int*)p;   p += e_i;
        int* srcs   = (int*)p;   p += e_i;
        int* dsts   = (int*)p;   p += e_i;
        float* Pa   = (float*)p; p += p_b;
        float* Pb   = (float*)p;

        hipMemsetAsync(deg, 0, n_i, stream);
        hist_kernel<<<(E + 255) / 256, 256, 0, stream>>>(dst, deg, E);
        scanA_kernel<<<NP, 256, 0, stream>>>(deg, part, N);
        scanB_kernel<<<1, 256, 0, stream>>>(part, NP);
        scanC_kernel<<<NP, 256, 0, stream>>>(deg, part, cursor, N);
        build2_kernel<<<(E + 255) / 256, 256, 0, stream>>>(dst, src, cursor,
                                                           eidx, srcs, dsts, E);
        pre_kernel<<<(N + TN - 1) / TN, 256, 0, stream>>>(node_feat, W_e1, b_e1,
                                                          Pa, Pb, N);
        const int dblocks2 = (N + DPB - 1) / DPB;
        edge_kernel2<<<dblocks2, 256, 0, stream>>>(Pa, Pb, coord, edge_feat,
                                                   eidx, srcs, dsts, cursor, deg,
                                                   W_e1, W_e2, b_e2, h_neigh, N);
    }

    const int nblocks = (N + TN - 1) / TN;
    node_kernel<<<nblocks, 256, 0, stream>>>(node_feat, h_neigh,
                                             W_n1, b_n1, W_n2, b_n2,
                                             (float*)d_out, N);
}